// Round 1
// baseline (394.585 us; speedup 1.0000x reference)
//
#include <hip/hip_runtime.h>
#include <math.h>

// Problem constants
constexpr int kB = 256, kC = 512, kT = 56, kP = 512;
constexpr float kEps = 1e-8f;
// Tiling
constexpr int BB = 16;      // b rows per block
constexpr int PP = 16;      // p rows per block
constexpr int CCH = 8;      // c chunk staged per iteration
constexpr int TG = 14;      // T/4 float4 groups
constexpr int CT = kC * kT; // 28672 floats per (b) or (p) row

// ---------------------------------------------------------------------------
// norms: dst[n*T+t] = sqrt( sum_c src[n*C*T + c*T + t]^2 )   (one block per n)
// ---------------------------------------------------------------------------
__global__ __launch_bounds__(256) void norms_kernel(const float* __restrict__ src,
                                                    float* __restrict__ dst) {
  const int n = blockIdx.x;
  const int t = threadIdx.x & 63;
  const int wq = threadIdx.x >> 6;
  const float* base = src + (size_t)n * CT;
  float acc = 0.f;
  if (t < kT) {
    const int cbeg = wq * (kC / 4), cend = cbeg + kC / 4;
    for (int c = cbeg; c < cend; ++c) {
      float v = base[c * kT + t];
      acc = fmaf(v, v, acc);
    }
  }
  __shared__ float part[4][64];
  part[wq][t] = acc;
  __syncthreads();
  if (wq == 0 && t < kT) {
    dst[n * kT + t] = sqrtf(part[0][t] + part[1][t] + part[2][t] + part[3][t]);
  }
}

// ---------------------------------------------------------------------------
// main: per (b,p) pair accumulate dots[t], wdots[t] over c, then softmax over
// t and the fc reduction. One thread owns one (b,p) pair; block = 16b x 16p.
// LDS tiles are stored interleaved as [c][tg][row] float4 so that:
//   - staging writes are linear (slot k = thread's k) -> conflict-free b128
//   - staging global reads coalesce (each wave: 16 rows x 64B contiguous)
//   - compute reads are contiguous chunks (p: 16 consecutive -> 2-way max;
//     x: 4 consecutive, 16-lane broadcast)
// ---------------------------------------------------------------------------
__global__ __launch_bounds__(256) void proto_main_kernel(
    const float* __restrict__ x, const float* __restrict__ proto,
    const float* __restrict__ fcw, const float* __restrict__ fcb,
    const float* __restrict__ xn, const float* __restrict__ pn,
    float* __restrict__ out) {
  __shared__ float4 xs4[BB * CCH * TG];  // 1792 float4 = 28672 B
  __shared__ float4 ps4[PP * CCH * TG];  // 28672 B
  __shared__ float fw[kC];               // 2048 B

  const int tid = threadIdx.x;
  const int pi = tid & 15;
  const int bi = tid >> 4;
  const int b0 = blockIdx.y * BB;
  const int p0 = blockIdx.x * PP;

  fw[tid] = fcw[tid];
  fw[tid + 256] = fcw[tid + 256];

  // Precompute per-thread staging offsets (identical geometry for x and p tiles).
  // Linear float4 slot k = tid + 256*i ; row = k&15 ; r=k>>4 ; c=r/14 ; tg=r%14
  int off[7];
#pragma unroll
  for (int i = 0; i < 7; ++i) {
    int k = tid + 256 * i;
    int row = k & 15;
    int r = k >> 4;
    int c = r / TG;
    int tg = r - c * TG;
    off[i] = row * CT + c * kT + tg * 4;  // float units
  }
  const float* Xb = x + (size_t)b0 * CT;
  const float* Pb = proto + (size_t)p0 * CT;

  float d[kT];
  float w[kT];
#pragma unroll
  for (int t = 0; t < kT; ++t) { d[t] = 0.f; w[t] = 0.f; }

#pragma unroll 1
  for (int ch = 0; ch < kC / CCH; ++ch) {
    const int cofs = ch * (CCH * kT);
#pragma unroll
    for (int i = 0; i < 7; ++i) {
      float4 vx = *(const float4*)(Xb + off[i] + cofs);
      float4 vp = *(const float4*)(Pb + off[i] + cofs);
      xs4[tid + 256 * i] = vx;
      ps4[tid + 256 * i] = vp;
    }
    __syncthreads();
#pragma unroll 1
    for (int c = 0; c < CCH; ++c) {
      const float fcwc = fw[ch * CCH + c];
      const float4* xr = xs4 + c * (TG * BB) + bi;
      const float4* pr = ps4 + c * (TG * PP) + pi;
#pragma unroll
      for (int tg = 0; tg < TG; ++tg) {
        float4 xa = xr[tg * BB];
        float4 pa = pr[tg * PP];
        float m0 = xa.x * pa.x;
        float m1 = xa.y * pa.y;
        float m2 = xa.z * pa.z;
        float m3 = xa.w * pa.w;
        d[tg * 4 + 0] += m0; w[tg * 4 + 0] = fmaf(m0, fcwc, w[tg * 4 + 0]);
        d[tg * 4 + 1] += m1; w[tg * 4 + 1] = fmaf(m1, fcwc, w[tg * 4 + 1]);
        d[tg * 4 + 2] += m2; w[tg * 4 + 2] = fmaf(m2, fcwc, w[tg * 4 + 2]);
        d[tg * 4 + 3] += m3; w[tg * 4 + 3] = fmaf(m3, fcwc, w[tg * 4 + 3]);
      }
    }
    __syncthreads();
  }

  // Epilogue: sim = dots / max(xn*pn, eps); softmax over t; out = relu(sum att*wdots + b)
  const float* xnr = xn + (size_t)(b0 + bi) * kT;
  const float* pnr = pn + (size_t)(p0 + pi) * kT;
  float mx = -3.0e38f;
#pragma unroll
  for (int t = 0; t < kT; ++t) {
    float dn = fmaxf(xnr[t] * pnr[t], kEps);
    float s = d[t] / dn;
    d[t] = s;
    mx = fmaxf(mx, s);
  }
  float se = 0.f, num = 0.f;
#pragma unroll
  for (int t = 0; t < kT; ++t) {
    float e = expf(d[t] - mx);
    se += e;
    num = fmaf(e, w[t], num);
  }
  float o = num / se + fcb[0];
  out[(size_t)(b0 + bi) * kP + (p0 + pi)] = fmaxf(o, 0.f);
}

// ---------------------------------------------------------------------------
extern "C" void kernel_launch(void* const* d_in, const int* in_sizes, int n_in,
                              void* d_out, int out_size, void* d_ws, size_t ws_size,
                              hipStream_t stream) {
  const float* x = (const float*)d_in[0];      // (B, C, H, W) = (B, C, T)
  const float* proto = (const float*)d_in[1];  // (P, C, T)
  const float* fcw = (const float*)d_in[2];    // (1, C)
  const float* fcb = (const float*)d_in[3];    // (1,)
  float* out = (float*)d_out;                  // (B, P)

  float* xn = (float*)d_ws;       // B*T floats
  float* pn = xn + kB * kT;       // P*T floats

  hipLaunchKernelGGL(norms_kernel, dim3(kB), dim3(256), 0, stream, x, xn);
  hipLaunchKernelGGL(norms_kernel, dim3(kP), dim3(256), 0, stream, proto, pn);
  hipLaunchKernelGGL(proto_main_kernel, dim3(kP / PP, kB / BB), dim3(256), 0, stream,
                     x, proto, fcw, fcb, xn, pn, out);
}

// Round 2
// 194.088 us; speedup vs baseline: 2.0330x; 2.0330x over previous
//
#include <hip/hip_runtime.h>
#include <hip/hip_bf16.h>
#include <math.h>

// Problem constants
constexpr int kB = 256, kC = 512, kT = 56, kP = 512;

typedef short v4s __attribute__((ext_vector_type(4)));
typedef float v4f __attribute__((ext_vector_type(4)));

__device__ __forceinline__ unsigned pack_bf16(float a, float b) {
  __hip_bfloat16 ha = __float2bfloat16(a);
  __hip_bfloat16 hb = __float2bfloat16(b);
  unsigned short ua, ub;
  __builtin_memcpy(&ua, &ha, 2);
  __builtin_memcpy(&ub, &hb, 2);
  return (unsigned)ua | ((unsigned)ub << 16);
}

__device__ __forceinline__ v4s frag2(unsigned w0, unsigned w1) {
  unsigned u[2] = {w0, w1};
  v4s s;
  __builtin_memcpy(&s, u, 8);
  return s;
}

// One block = 32 b  x 16 p x all 56 t.  1024 threads = 16 waves = 2 bq x 8 tq.
// K-loop over C in chunks of 16; per chunk: stage x/p/p*fcw as packed bf16x2
// into LDS (odd strides -> <=2-way bank conflicts on both write (lanes=t) and
// frag-read (lanes=(row,q)) patterns), then per wave 7 t x 2 MFMA 16x16x16.
// Norms are accumulated in fp32 during staging (each thread ends up owning
// complete xn^2[b][t] / pn^2[p][t] values - no extra kernel, no cross-thread
// reduction). Epilogue: per-wave partial softmax over its 7 t, then
// log-sum-exp merge across the 8 t-groups via LDS.
__global__ __launch_bounds__(1024) void proto_mfma_kernel(
    const float* __restrict__ x, const float* __restrict__ proto,
    const float* __restrict__ fcw, const float* __restrict__ fcb,
    float* __restrict__ out) {
  // word strides: x row (8 words + 1 pad) = 9; x t-stride = 32*9+1 = 289
  //               p row 9; p t-stride = 16*9+1 = 145
  __shared__ unsigned xs[56 * 289];   // 64,736 B
  __shared__ unsigned ps[56 * 145];   // 32,480 B
  __shared__ unsigned pws[56 * 145];  // 32,480 B   (total 129,696 B)

  const int tid = threadIdx.x;
  const int l = tid & 63;
  const int w = tid >> 6;   // wave 0..15
  const int bq = w & 1;     // b quadrant (16 rows each)
  const int tq = w >> 1;    // t group 0..7
  const int t0 = tq * 7;

  // XCD swizzle: consecutive linear block ids round-robin XCDs; give each XCD
  // one 32-row b-slice (3.67 MB fp32 -> L2-resident) and all 32 p-blocks.
  const int n = blockIdx.y * 32 + blockIdx.x;  // 0..255
  const int p0 = (n >> 3) * 16;
  const int b0 = (n & 7) * 32;

  const bool act = (l < 56);
  const int lt = l;  // staging lane's t

  // staging global bases (dword indices; max ~14.7e6, fits int)
  const int xbase0 = ((b0 + 2 * w + 0) * kC) * kT + lt;
  const int xbase1 = ((b0 + 2 * w + 1) * kC) * kT + lt;
  const int pbase = ((p0 + w) * kC) * kT + lt;

  // compute-side fragment offsets
  const int arow = l & 15;        // A: m-row / B: n-col
  const int q2 = (l >> 4) << 1;   // word offset for k-group
  const int xoff = (bq * 16 + arow) * 9 + q2;
  const int poff = arow * 9 + q2;

  v4f acc[7][2];
#pragma unroll
  for (int ti = 0; ti < 7; ++ti) {
    acc[ti][0] = v4f{0.f, 0.f, 0.f, 0.f};
    acc[ti][1] = v4f{0.f, 0.f, 0.f, 0.f};
  }
  float xn2a = 0.f, xn2b = 0.f, pn2 = 0.f;

#pragma unroll 1
  for (int st = 0; st < 32; ++st) {
    const int k0 = st * 16;
    if (act) {
      // x: this thread stages rows b = 2w, 2w+1 for all 8 c-pairs at t = lt
#pragma unroll
      for (int r = 0; r < 16; ++r) {
        const int cw = r & 7;
        const int c = k0 + 2 * cw;
        const int ga = ((r >> 3) ? xbase1 : xbase0) + c * kT;
        float g0 = x[ga], g1 = x[ga + kT];
        if (r >> 3)
          xn2b = fmaf(g0, g0, fmaf(g1, g1, xn2b));
        else
          xn2a = fmaf(g0, g0, fmaf(g1, g1, xn2a));
        xs[lt * 289 + (2 * w + (r >> 3)) * 9 + cw] = pack_bf16(g0, g1);
      }
      // p: wave w stages p-row w
#pragma unroll
      for (int cw = 0; cw < 8; ++cw) {
        const int c = k0 + 2 * cw;
        const int ga = pbase + c * kT;
        float g0 = proto[ga], g1 = proto[ga + kT];
        pn2 = fmaf(g0, g0, fmaf(g1, g1, pn2));
        ps[lt * 145 + w * 9 + cw] = pack_bf16(g0, g1);
        float f0 = fcw[c], f1 = fcw[c + 1];
        pws[lt * 145 + w * 9 + cw] = pack_bf16(g0 * f0, g1 * f1);
      }
    }
    __syncthreads();
#pragma unroll
    for (int ti = 0; ti < 7; ++ti) {
      const int t = t0 + ti;
      unsigned xw0 = xs[t * 289 + xoff];
      unsigned xw1 = xs[t * 289 + xoff + 1];
      unsigned pw0 = ps[t * 145 + poff];
      unsigned pw1 = ps[t * 145 + poff + 1];
      unsigned ww0 = pws[t * 145 + poff];
      unsigned ww1 = pws[t * 145 + poff + 1];
      v4s af = frag2(xw0, xw1);
      v4s bf = frag2(pw0, pw1);
      v4s wf = frag2(ww0, ww1);
      acc[ti][0] = __builtin_amdgcn_mfma_f32_16x16x16bf16_1k(af, bf, acc[ti][0], 0, 0, 0);
      acc[ti][1] = __builtin_amdgcn_mfma_f32_16x16x16bf16_1k(af, wf, acc[ti][1], 0, 0, 0);
    }
    __syncthreads();
  }

  // publish fused norms (complete per-thread sums) into reused LDS (ps region)
  float* xnorm = (float*)ps;          // [32][56] = xn^2
  float* pnorm = xnorm + 32 * 56;     // [16][56] = pn^2
  if (act) {
    xnorm[(2 * w + 0) * 56 + lt] = xn2a;
    xnorm[(2 * w + 1) * 56 + lt] = xn2b;
    pnorm[w * 56 + lt] = pn2;
  }
  __syncthreads();

  // per-wave partial softmax over its 7 t, per output pair
  float* fm = (float*)xs;             // [8][512] max
  float* fsum = fm + 4096;            // [8][512] sum exp
  float* fnum = fsum + 4096;          // [8][512] sum exp*wdots
  const int pc = arow;
  const int qq = l >> 4;
#pragma unroll
  for (int i = 0; i < 4; ++i) {
    const int bl = bq * 16 + 4 * qq + i;  // D row = (l>>4)*4 + i (m89-verified)
    float m = -3.0e38f;
    float sims[7];
#pragma unroll
    for (int ti = 0; ti < 7; ++ti) {
      const int t = t0 + ti;
      float den = fmaxf(sqrtf(xnorm[bl * 56 + t]) * sqrtf(pnorm[pc * 56 + t]), 1e-8f);
      float s = acc[ti][0][i] / den;
      sims[ti] = s;
      m = fmaxf(m, s);
    }
    float se = 0.f, nu = 0.f;
#pragma unroll
    for (int ti = 0; ti < 7; ++ti) {
      float e = __expf(sims[ti] - m);
      se += e;
      nu = fmaf(e, acc[ti][1][i], nu);
    }
    const int pair = bl * 16 + pc;
    fm[tq * 512 + pair] = m;
    fsum[tq * 512 + pair] = se;
    fnum[tq * 512 + pair] = nu;
  }
  __syncthreads();

  // merge the 8 t-group partials (log-sum-exp) and write out
  if (tid < 512) {
    float M = -3.0e38f;
#pragma unroll
    for (int k = 0; k < 8; ++k) M = fmaxf(M, fm[k * 512 + tid]);
    float S = 0.f, N = 0.f;
#pragma unroll
    for (int k = 0; k < 8; ++k) {
      float sc = __expf(fm[k * 512 + tid] - M);
      S = fmaf(fsum[k * 512 + tid], sc, S);
      N = fmaf(fnum[k * 512 + tid], sc, N);
    }
    float o = N / S + fcb[0];
    out[(b0 + (tid >> 4)) * kP + p0 + (tid & 15)] = fmaxf(o, 0.f);
  }
}

extern "C" void kernel_launch(void* const* d_in, const int* in_sizes, int n_in,
                              void* d_out, int out_size, void* d_ws, size_t ws_size,
                              hipStream_t stream) {
  const float* x = (const float*)d_in[0];      // (B, C, T)
  const float* proto = (const float*)d_in[1];  // (P, C, T)
  const float* fcw = (const float*)d_in[2];    // (1, C)
  const float* fcb = (const float*)d_in[3];    // (1,)
  float* out = (float*)d_out;                  // (B, P)

  hipLaunchKernelGGL(proto_mfma_kernel, dim3(32, 8), dim3(1024), 0, stream,
                     x, proto, fcw, fcb, out);
}

// Round 3
// 89.531 us; speedup vs baseline: 4.4072x; 2.1678x over previous
//
#include <hip/hip_runtime.h>
#include <hip/hip_bf16.h>
#include <math.h>

// Problem constants
constexpr int kB = 256, kC = 512, kT = 56, kP = 512;
constexpr int kCT = kC * kT;  // 28672 floats per row

typedef short v4s __attribute__((ext_vector_type(4)));
typedef float v4f __attribute__((ext_vector_type(4)));

__device__ __forceinline__ unsigned pack_bf16(float a, float b) {
  __hip_bfloat16 ha = __float2bfloat16(a);
  __hip_bfloat16 hb = __float2bfloat16(b);
  unsigned short ua, ub;
  __builtin_memcpy(&ua, &ha, 2);
  __builtin_memcpy(&ub, &hb, 2);
  return (unsigned)ua | ((unsigned)ub << 16);
}

__device__ __forceinline__ v4s frag2(unsigned w0, unsigned w1) {
  unsigned u[2] = {w0, w1};
  v4s s;
  __builtin_memcpy(&s, u, 8);
  return s;
}

// ===========================================================================
// PREP: per source row (b or p): read fp32 once (coalesced), transpose via
// LDS, write bf16-packed t-major words:
//   xt [(t*256 + b)*256 + cw]   = pack(x[b][2cw][t],   x[b][2cw+1][t])
//   xwt[(t*256 + b)*256 + cw]   = same * fcw           (fc folded into A-side)
//   pt [(t*512 + p)*256 + cw]
// plus fused norms xn[b*56+t], pn[p*56+t].
// ===========================================================================
__global__ __launch_bounds__(512) void prep_kernel(
    const float* __restrict__ x, const float* __restrict__ proto,
    const float* __restrict__ fcw,
    unsigned* __restrict__ xt, unsigned* __restrict__ xwt,
    unsigned* __restrict__ pt,
    float* __restrict__ xn, float* __restrict__ pn) {
  __shared__ float tile[512 * 57];  // [c][t], pad 57
  __shared__ float fws[512];
  __shared__ float part[8][64];

  const int tid = threadIdx.x;
  const int n = blockIdx.x;
  const bool isx = (n < kB);
  const int row = isx ? n : (n - kB);
  const float* src = (isx ? x + (size_t)row * kCT : proto + (size_t)row * kCT);

  fws[tid] = fcw[tid & 511];

  // stage full row, scatter-transpose to tile[c][t]
#pragma unroll 1
  for (int it = 0; it < 14; ++it) {
    const int f0 = it * 2048 + tid * 4;
    float4 v = *(const float4*)(src + f0);
#pragma unroll
    for (int j = 0; j < 4; ++j) {
      int f = f0 + j;
      int c = (int)(((unsigned)f * 74899u) >> 22);  // f / 56
      int t = f - c * 56;
      tile[c * 57 + t] = ((const float*)&v)[j];
    }
  }
  __syncthreads();

  // fused norms: 8 c-slices of 64, lanes = t
  {
    const int g = tid >> 6, tt = tid & 63;
    float a = 0.f;
    if (tt < 56) {
      for (int c = g * 64; c < g * 64 + 64; ++c) {
        float u = tile[c * 57 + tt];
        a = fmaf(u, u, a);
      }
    }
    part[g][tt] = a;
  }
  __syncthreads();
  if (tid < 56) {
    float s = 0.f;
#pragma unroll
    for (int g = 0; g < 8; ++g) s += part[g][tid];
    float r = sqrtf(s);
    if (isx) xn[row * 56 + tid] = r; else pn[row * 56 + tid] = r;
  }

  // pack + transposed write (coalesced 1KB stores)
#pragma unroll 1
  for (int it = 0; it < 28; ++it) {
    const int id = it * 512 + tid;       // 0..14335
    const int t = id >> 8;
    const int cw = id & 255;
    float g0 = tile[(2 * cw) * 57 + t];
    float g1 = tile[(2 * cw + 1) * 57 + t];
    unsigned wd = pack_bf16(g0, g1);
    if (isx) {
      size_t o = ((size_t)(t * kB + row)) * 256 + cw;
      xt[o] = wd;
      xwt[o] = pack_bf16(g0 * fws[2 * cw], g1 * fws[2 * cw + 1]);
    } else {
      pt[((size_t)(t * kP + row)) * 256 + cw] = wd;
    }
  }
}

// ===========================================================================
// MAIN: block = 64b x 64p x 7t (grid 4 x 8 x 8 = 256 = 1/CU), 8 waves
// (4 m-waves x 2 n-waves, wave tile 16b x 32p). Flash-style online softmax
// over t. K-chunks of 64 words (128 c), double-buffered, reg-staged with
// issue-early/write-late. LDS row stride 68 words: conflict-free for both
// ds_write_b128 staging and ds_read_b64 fragment reads (start banks
// 4(r+q) mod 32, uniform 8-per-bank coverage).
// ===========================================================================
constexpr int KCW = 64;    // chunk words (=128 c)
constexpr int RSTR = 68;   // padded LDS row stride (words)
constexpr int TSZ = 64 * RSTR;     // one tile: 4352 words
constexpr int BUFW = 3 * TSZ;      // x + xw + p per buffer: 13056 words

__global__ __launch_bounds__(512) void proto_gemm_kernel(
    const unsigned* __restrict__ xt, const unsigned* __restrict__ xwt,
    const unsigned* __restrict__ pt,
    const float* __restrict__ xn, const float* __restrict__ pn,
    float* __restrict__ part) {
  __shared__ __align__(16) unsigned lds[2 * BUFW];  // 104,448 B

  const int tid = threadIdx.x;
  const int l = tid & 63;
  const int w = tid >> 6;
  const int wm = w & 3;   // b rows wm*16..
  const int wn = w >> 2;  // p cols wn*32..
  const int b0 = blockIdx.x * 64;
  const int p0 = blockIdx.y * 64;
  const int tg = blockIdx.z;  // t = tg*7 .. tg*7+6

  // staging geometry: ids {tid, tid+512}: row = id>>4, col = (id&15)*4
  const int sr0 = tid >> 4;
  const int sr1 = sr0 + 32;
  const int sc = (tid & 15) * 4;
  const int lw0 = sr0 * RSTR + sc;
  const int lw1 = sr1 * RSTR + sc;

  // fragment addresses (words, within a tile)
  const int fr = l & 15;
  const int fq = (l >> 4) * 2;
  const int ax = (wm * 16 + fr) * RSTR + fq;
  const int ap0 = (wn * 32 + fr) * RSTR + fq;
  const int ap1 = ap0 + 16 * RSTR;

  v4f aD0, aD1, aW0, aW1;
  aD0 = aD1 = aW0 = aW1 = v4f{0.f, 0.f, 0.f, 0.f};
  v4f m0v, m1v, s0v, s1v, n0v, n1v;
  m0v = m1v = v4f{-3.0e38f, -3.0e38f, -3.0e38f, -3.0e38f};
  s0v = s1v = n0v = n1v = v4f{0.f, 0.f, 0.f, 0.f};

  uint4 rx0, rx1, rw0, rw1, rp0, rp1;

  auto load_regs = [&](int cc) {
    const int t = tg * 7 + (cc >> 2);
    const int w0 = (cc & 3) * KCW;
    const unsigned* gx = xt + ((size_t)(t * kB + b0)) * 256 + w0 + sc;
    const unsigned* gw = xwt + ((size_t)(t * kB + b0)) * 256 + w0 + sc;
    const unsigned* gp = pt + ((size_t)(t * kP + p0)) * 256 + w0 + sc;
    rx0 = *(const uint4*)(gx + (size_t)sr0 * 256);
    rx1 = *(const uint4*)(gx + (size_t)sr1 * 256);
    rw0 = *(const uint4*)(gw + (size_t)sr0 * 256);
    rw1 = *(const uint4*)(gw + (size_t)sr1 * 256);
    rp0 = *(const uint4*)(gp + (size_t)sr0 * 256);
    rp1 = *(const uint4*)(gp + (size_t)sr1 * 256);
  };
  auto store_lds = [&](int cc) {
    unsigned* buf = lds + (cc & 1) * BUFW;
    *(uint4*)(buf + lw0) = rx0;
    *(uint4*)(buf + lw1) = rx1;
    *(uint4*)(buf + TSZ + lw0) = rw0;
    *(uint4*)(buf + TSZ + lw1) = rw1;
    *(uint4*)(buf + 2 * TSZ + lw0) = rp0;
    *(uint4*)(buf + 2 * TSZ + lw1) = rp1;
  };

  // prologue
  load_regs(0);
  store_lds(0);
  __syncthreads();

#pragma unroll 1
  for (int cc = 0; cc < 28; ++cc) {
    if (cc < 27) load_regs(cc + 1);

    const unsigned* bx = lds + (cc & 1) * BUFW;
    const unsigned* bw = bx + TSZ;
    const unsigned* bp = bx + 2 * TSZ;
#pragma unroll
    for (int kk = 0; kk < 8; ++kk) {
      uint2 xr = *(const uint2*)(bx + ax + 8 * kk);
      uint2 wr = *(const uint2*)(bw + ax + 8 * kk);
      uint2 pr0 = *(const uint2*)(bp + ap0 + 8 * kk);
      uint2 pr1 = *(const uint2*)(bp + ap1 + 8 * kk);
      v4s xf = frag2(xr.x, xr.y);
      v4s wf = frag2(wr.x, wr.y);
      v4s pf0 = frag2(pr0.x, pr0.y);
      v4s pf1 = frag2(pr1.x, pr1.y);
      aD0 = __builtin_amdgcn_mfma_f32_16x16x16bf16_1k(xf, pf0, aD0, 0, 0, 0);
      aD1 = __builtin_amdgcn_mfma_f32_16x16x16bf16_1k(xf, pf1, aD1, 0, 0, 0);
      aW0 = __builtin_amdgcn_mfma_f32_16x16x16bf16_1k(wf, pf0, aW0, 0, 0, 0);
      aW1 = __builtin_amdgcn_mfma_f32_16x16x16bf16_1k(wf, pf1, aW1, 0, 0, 0);
    }

    if ((cc & 3) == 3) {
      // end of one t: online softmax update
      const int t = tg * 7 + (cc >> 2);
      const int brow = b0 + wm * 16 + (l >> 4) * 4;
      float xnv[4];
#pragma unroll
      for (int i = 0; i < 4; ++i) xnv[i] = xn[(brow + i) * 56 + t];
      const float pnv0 = pn[(p0 + wn * 32 + fr) * 56 + t];
      const float pnv1 = pn[(p0 + wn * 32 + 16 + fr) * 56 + t];
#pragma unroll
      for (int i = 0; i < 4; ++i) {
        {
          float den = fmaxf(xnv[i] * pnv0, 1e-8f);
          float sim = aD0[i] * __builtin_amdgcn_rcpf(den);
          float mo = m0v[i];
          float mn = fmaxf(mo, sim);
          float cs = __expf(mo - mn);
          float e = __expf(sim - mn);
          s0v[i] = s0v[i] * cs + e;
          n0v[i] = fmaf(e, aW0[i], n0v[i] * cs);
          m0v[i] = mn;
        }
        {
          float den = fmaxf(xnv[i] * pnv1, 1e-8f);
          float sim = aD1[i] * __builtin_amdgcn_rcpf(den);
          float mo = m1v[i];
          float mn = fmaxf(mo, sim);
          float cs = __expf(mo - mn);
          float e = __expf(sim - mn);
          s1v[i] = s1v[i] * cs + e;
          n1v[i] = fmaf(e, aW1[i], n1v[i] * cs);
          m1v[i] = mn;
        }
      }
      aD0 = aD1 = aW0 = aW1 = v4f{0.f, 0.f, 0.f, 0.f};
    }

    __syncthreads();
    if (cc < 27) {
      store_lds(cc + 1);
    }
    __syncthreads();
  }

  // write partials: part[(tg*3 + comp)*131072 + b*512 + p]
  float* pm = part + ((size_t)tg * 3 + 0) * 131072;
  float* ps = part + ((size_t)tg * 3 + 1) * 131072;
  float* pu = part + ((size_t)tg * 3 + 2) * 131072;
#pragma unroll
  for (int i = 0; i < 4; ++i) {
    const int bg = b0 + wm * 16 + (l >> 4) * 4 + i;
    {
      const size_t o = (size_t)bg * 512 + p0 + wn * 32 + fr;
      pm[o] = m0v[i]; ps[o] = s0v[i]; pu[o] = n0v[i];
    }
    {
      const size_t o = (size_t)bg * 512 + p0 + wn * 32 + 16 + fr;
      pm[o] = m1v[i]; ps[o] = s1v[i]; pu[o] = n1v[i];
    }
  }
}

// ===========================================================================
// MERGE: combine the 8 t-group partials (log-sum-exp), + bias, relu.
// ===========================================================================
__global__ __launch_bounds__(256) void merge_kernel(
    const float* __restrict__ part, const float* __restrict__ fcb,
    float* __restrict__ out) {
  const int pair = blockIdx.x * 256 + threadIdx.x;
  float M = -3.0e38f;
#pragma unroll
  for (int k = 0; k < 8; ++k) M = fmaxf(M, part[((size_t)k * 3) * 131072 + pair]);
  float S = 0.f, N = 0.f;
#pragma unroll
  for (int k = 0; k < 8; ++k) {
    float mk = part[((size_t)k * 3) * 131072 + pair];
    float sc = __expf(mk - M);
    S = fmaf(part[((size_t)k * 3 + 1) * 131072 + pair], sc, S);
    N = fmaf(part[((size_t)k * 3 + 2) * 131072 + pair], sc, N);
  }
  float o = N * __builtin_amdgcn_rcpf(S) + fcb[0];
  out[pair] = fmaxf(o, 0.f);
}

// ===========================================================================
// FALLBACK (round-2 kernel, used only if ws_size is too small)
// ===========================================================================
__global__ __launch_bounds__(1024) void proto_mfma_kernel(
    const float* __restrict__ x, const float* __restrict__ proto,
    const float* __restrict__ fcw, const float* __restrict__ fcb,
    float* __restrict__ out) {
  __shared__ unsigned xs[56 * 289];
  __shared__ unsigned ps[56 * 145];
  __shared__ unsigned pws[56 * 145];

  const int tid = threadIdx.x;
  const int l = tid & 63;
  const int w = tid >> 6;
  const int bq = w & 1;
  const int tq = w >> 1;
  const int t0 = tq * 7;

  const int n = blockIdx.y * 32 + blockIdx.x;
  const int p0 = (n >> 3) * 16;
  const int b0 = (n & 7) * 32;

  const bool act = (l < 56);
  const int lt = l;

  const int xbase0 = ((b0 + 2 * w + 0) * kC) * kT + lt;
  const int xbase1 = ((b0 + 2 * w + 1) * kC) * kT + lt;
  const int pbase = ((p0 + w) * kC) * kT + lt;

  const int arow = l & 15;
  const int q2 = (l >> 4) << 1;
  const int xoff = (bq * 16 + arow) * 9 + q2;
  const int poff = arow * 9 + q2;

  v4f acc[7][2];
#pragma unroll
  for (int ti = 0; ti < 7; ++ti) {
    acc[ti][0] = v4f{0.f, 0.f, 0.f, 0.f};
    acc[ti][1] = v4f{0.f, 0.f, 0.f, 0.f};
  }
  float xn2a = 0.f, xn2b = 0.f, pn2 = 0.f;

#pragma unroll 1
  for (int st = 0; st < 32; ++st) {
    const int k0 = st * 16;
    if (act) {
#pragma unroll
      for (int r = 0; r < 16; ++r) {
        const int cw = r & 7;
        const int c = k0 + 2 * cw;
        const int ga = ((r >> 3) ? xbase1 : xbase0) + c * kT;
        float g0 = x[ga], g1 = x[ga + kT];
        if (r >> 3) xn2b = fmaf(g0, g0, fmaf(g1, g1, xn2b));
        else xn2a = fmaf(g0, g0, fmaf(g1, g1, xn2a));
        xs[lt * 289 + (2 * w + (r >> 3)) * 9 + cw] = pack_bf16(g0, g1);
      }
#pragma unroll
      for (int cw = 0; cw < 8; ++cw) {
        const int c = k0 + 2 * cw;
        const int ga = pbase + c * kT;
        float g0 = proto[ga], g1 = proto[ga + kT];
        pn2 = fmaf(g0, g0, fmaf(g1, g1, pn2));
        ps[lt * 145 + w * 9 + cw] = pack_bf16(g0, g1);
        float f0 = fcw[c], f1 = fcw[c + 1];
        pws[lt * 145 + w * 9 + cw] = pack_bf16(g0 * f0, g1 * f1);
      }
    }
    __syncthreads();
#pragma unroll
    for (int ti = 0; ti < 7; ++ti) {
      const int t = t0 + ti;
      unsigned xw0 = xs[t * 289 + xoff];
      unsigned xw1 = xs[t * 289 + xoff + 1];
      unsigned pw0 = ps[t * 145 + poff];
      unsigned pw1 = ps[t * 145 + poff + 1];
      unsigned ww0 = pws[t * 145 + poff];
      unsigned ww1 = pws[t * 145 + poff + 1];
      v4s af = frag2(xw0, xw1);
      v4s bf = frag2(pw0, pw1);
      v4s wf = frag2(ww0, ww1);
      acc[ti][0] = __builtin_amdgcn_mfma_f32_16x16x16bf16_1k(af, bf, acc[ti][0], 0, 0, 0);
      acc[ti][1] = __builtin_amdgcn_mfma_f32_16x16x16bf16_1k(af, wf, acc[ti][1], 0, 0, 0);
    }
    __syncthreads();
  }

  float* xnorm = (float*)ps;
  float* pnorm = xnorm + 32 * 56;
  if (act) {
    xnorm[(2 * w + 0) * 56 + lt] = xn2a;
    xnorm[(2 * w + 1) * 56 + lt] = xn2b;
    pnorm[w * 56 + lt] = pn2;
  }
  __syncthreads();

  float* fm = (float*)xs;
  float* fsum = fm + 4096;
  float* fnum = fsum + 4096;
  const int pc = arow;
  const int qq = l >> 4;
#pragma unroll
  for (int i = 0; i < 4; ++i) {
    const int bl = bq * 16 + 4 * qq + i;
    float m = -3.0e38f;
    float sims[7];
#pragma unroll
    for (int ti = 0; ti < 7; ++ti) {
      const int t = t0 + ti;
      float den = fmaxf(sqrtf(xnorm[bl * 56 + t]) * sqrtf(pnorm[pc * 56 + t]), 1e-8f);
      float s = acc[ti][0][i] / den;
      sims[ti] = s;
      m = fmaxf(m, s);
    }
    float se = 0.f, nu = 0.f;
#pragma unroll
    for (int ti = 0; ti < 7; ++ti) {
      float e = __expf(sims[ti] - m);
      se += e;
      nu = fmaf(e, acc[ti][1][i], nu);
    }
    const int pair = bl * 16 + pc;
    fm[tq * 512 + pair] = m;
    fsum[tq * 512 + pair] = se;
    fnum[tq * 512 + pair] = nu;
  }
  __syncthreads();

  if (tid < 512) {
    float M = -3.0e38f;
#pragma unroll
    for (int k = 0; k < 8; ++k) M = fmaxf(M, fm[k * 512 + tid]);
    float S = 0.f, N = 0.f;
#pragma unroll
    for (int k = 0; k < 8; ++k) {
      float sc = __expf(fm[k * 512 + tid] - M);
      S = fmaf(fsum[k * 512 + tid], sc, S);
      N = fmaf(fnum[k * 512 + tid], sc, N);
    }
    float o = N / S + fcb[0];
    out[(b0 + (tid >> 4)) * kP + p0 + (tid & 15)] = fmaxf(o, 0.f);
  }
}

// ===========================================================================
extern "C" void kernel_launch(void* const* d_in, const int* in_sizes, int n_in,
                              void* d_out, int out_size, void* d_ws, size_t ws_size,
                              hipStream_t stream) {
  const float* x = (const float*)d_in[0];
  const float* proto = (const float*)d_in[1];
  const float* fcw = (const float*)d_in[2];
  const float* fcb = (const float*)d_in[3];
  float* out = (float*)d_out;

  // ws layout (words): xt 3,670,016 | xwt 3,670,016 | pt 7,340,032 |
  // part 3,145,728 | xn 14,336 | pn 28,672  => 17,868,800 words = 71,475,200 B
  const size_t need = 71475200;
  if (ws_size >= need) {
    unsigned* xt = (unsigned*)d_ws;
    unsigned* xwt = xt + 3670016;
    unsigned* ptb = xt + 7340032;
    float* partb = (float*)(xt + 14680064);
    float* xnb = (float*)(xt + 17825792);
    float* pnb = (float*)(xt + 17840128);

    hipLaunchKernelGGL(prep_kernel, dim3(kB + kP), dim3(512), 0, stream,
                       x, proto, fcw, xt, xwt, ptb, xnb, pnb);
    hipLaunchKernelGGL(proto_gemm_kernel, dim3(4, 8, 8), dim3(512), 0, stream,
                       xt, xwt, ptb, xnb, pnb, partb);
    hipLaunchKernelGGL(merge_kernel, dim3(512), dim3(256), 0, stream,
                       partb, fcb, out);
  } else {
    hipLaunchKernelGGL(proto_mfma_kernel, dim3(32, 8), dim3(1024), 0, stream,
                       x, proto, fcw, fcb, out);
  }
}

// Round 4
// 73.540 us; speedup vs baseline: 5.3656x; 1.2174x over previous
//
#include <hip/hip_runtime.h>
#include <hip/hip_bf16.h>
#include <math.h>

// Problem constants
constexpr int kB = 256, kC = 512, kT = 56, kP = 512;
constexpr int kCT = kC * kT;  // 28672 floats per row

typedef short v4s __attribute__((ext_vector_type(4)));
typedef short v8s __attribute__((ext_vector_type(8)));
typedef float v4f __attribute__((ext_vector_type(4)));

__device__ __forceinline__ unsigned pack_bf16(float a, float b) {
  __hip_bfloat16 ha = __float2bfloat16(a);
  __hip_bfloat16 hb = __float2bfloat16(b);
  unsigned short ua, ub;
  __builtin_memcpy(&ua, &ha, 2);
  __builtin_memcpy(&ub, &hb, 2);
  return (unsigned)ua | ((unsigned)ub << 16);
}

__device__ __forceinline__ v4s frag2(unsigned w0, unsigned w1) {
  unsigned u[2] = {w0, w1};
  v4s s;
  __builtin_memcpy(&s, u, 8);
  return s;
}

__device__ __forceinline__ v8s frag8(uint4 u) {
  v8s s;
  __builtin_memcpy(&s, &u, 16);
  return s;
}

// ===========================================================================
// PREP: per source row (b or p): read fp32 once (coalesced), transpose via
// LDS, write bf16-packed t-major words + fused norms. (unchanged from r3)
// ===========================================================================
__global__ __launch_bounds__(512) void prep_kernel(
    const float* __restrict__ x, const float* __restrict__ proto,
    const float* __restrict__ fcw,
    unsigned* __restrict__ xt, unsigned* __restrict__ xwt,
    unsigned* __restrict__ pt,
    float* __restrict__ xn, float* __restrict__ pn) {
  __shared__ float tile[512 * 57];
  __shared__ float fws[512];
  __shared__ float part[8][64];

  const int tid = threadIdx.x;
  const int n = blockIdx.x;
  const bool isx = (n < kB);
  const int row = isx ? n : (n - kB);
  const float* src = (isx ? x + (size_t)row * kCT : proto + (size_t)row * kCT);

  fws[tid] = fcw[tid & 511];

#pragma unroll 1
  for (int it = 0; it < 14; ++it) {
    const int f0 = it * 2048 + tid * 4;
    float4 v = *(const float4*)(src + f0);
#pragma unroll
    for (int j = 0; j < 4; ++j) {
      int f = f0 + j;
      int c = (int)(((unsigned)f * 74899u) >> 22);  // f / 56
      int t = f - c * 56;
      tile[c * 57 + t] = ((const float*)&v)[j];
    }
  }
  __syncthreads();

  {
    const int g = tid >> 6, tt = tid & 63;
    float a = 0.f;
    if (tt < 56) {
      for (int c = g * 64; c < g * 64 + 64; ++c) {
        float u = tile[c * 57 + tt];
        a = fmaf(u, u, a);
      }
    }
    part[g][tt] = a;
  }
  __syncthreads();
  if (tid < 56) {
    float s = 0.f;
#pragma unroll
    for (int g = 0; g < 8; ++g) s += part[g][tid];
    float r = sqrtf(s);
    if (isx) xn[row * 56 + tid] = r; else pn[row * 56 + tid] = r;
  }

#pragma unroll 1
  for (int it = 0; it < 28; ++it) {
    const int id = it * 512 + tid;
    const int t = id >> 8;
    const int cw = id & 255;
    float g0 = tile[(2 * cw) * 57 + t];
    float g1 = tile[(2 * cw + 1) * 57 + t];
    unsigned wd = pack_bf16(g0, g1);
    if (isx) {
      size_t o = ((size_t)(t * kB + row)) * 256 + cw;
      xt[o] = wd;
      xwt[o] = pack_bf16(g0 * fws[2 * cw], g1 * fws[2 * cw + 1]);
    } else {
      pt[((size_t)(t * kP + row)) * 256 + cw] = wd;
    }
  }
}

// ===========================================================================
// MAIN v2: block = 64b x 64p x 7t (grid 4x8x8 = 256 = 1/CU), 8 waves of
// 16b x 32p.  Changes vs r3:
//  - mfma_f32_16x16x32_bf16: b128 frag reads (half the DS instrs & MFMAs)
//  - LDS row stride 64 words + XOR swizzle col ^= (row&7)*4: lanes 0-15 of
//    each read hit 8 distinct bank-quads (all 32 banks) -> conflict floor
//  - single barrier per chunk, 2-deep named reg sets (A/B): store(cc+1) uses
//    regs loaded one full compute-phase earlier (counted vmcnt by compiler)
// ===========================================================================
constexpr int TSZ = 64 * 64;   // one tile: 4096 words (16 KB)
constexpr int BUF = 3 * TSZ;   // x + xw + p per buffer: 12288 words

__global__ __launch_bounds__(512) void proto_gemm_kernel(
    const unsigned* __restrict__ xt, const unsigned* __restrict__ xwt,
    const unsigned* __restrict__ pt,
    const float* __restrict__ xn, const float* __restrict__ pn,
    float* __restrict__ part) {
  __shared__ __align__(16) unsigned lds[2 * BUF];  // 98,304 B -> 1 block/CU

  const int tid = threadIdx.x;
  const int l = tid & 63;
  const int w = tid >> 6;
  const int wm = w & 3;   // b rows wm*16..
  const int wn = w >> 2;  // p cols wn*32..
  const int b0 = blockIdx.x * 64;
  const int p0 = blockIdx.y * 64;
  const int tg = blockIdx.z;  // t = tg*7 .. tg*7+6

  // staging: ids {tid, tid+512}: row = id>>4 (16 lanes/row), col = (id&15)*4
  const int sr0 = tid >> 4;
  const int sr1 = sr0 + 32;
  const int sc = (tid & 15) * 4;
  const int lw0 = sr0 * 64 + (sc ^ ((sr0 & 7) * 4));
  const int lw1 = sr1 * 64 + (sc ^ ((sr1 & 7) * 4));

  // fragment geometry (16x16x32: lane l -> row l&15, k-quarter l>>4)
  const int fr = l & 15;
  const int q = l >> 4;
  const int sw = (fr & 7) * 4;          // XOR swizzle for this lane's rows
  const int axr = (wm * 16 + fr) * 64;  // x/xw row base (words)
  const int ap0r = (wn * 32 + fr) * 64;
  const int ap1r = ap0r + 16 * 64;

  v4f aD0, aD1, aW0, aW1;
  aD0 = aD1 = aW0 = aW1 = v4f{0.f, 0.f, 0.f, 0.f};
  v4f m0v, m1v, s0v, s1v, n0v, n1v;
  m0v = m1v = v4f{-3.0e38f, -3.0e38f, -3.0e38f, -3.0e38f};
  s0v = s1v = n0v = n1v = v4f{0.f, 0.f, 0.f, 0.f};

  uint4 Ax0, Ax1, Aw0, Aw1, Ap0, Ap1;
  uint4 Bx0, Bx1, Bw0, Bw1, Bp0, Bp1;
  float xnv[4] = {0.f, 0.f, 0.f, 0.f};
  float pnv0 = 0.f, pnv1 = 0.f;

#define LOAD_REGS(S, CC) do { \
    const int t_ = tg * 7 + ((CC) >> 2); \
    const int w0_ = ((CC) & 3) * 64; \
    const unsigned* gx_ = xt + ((size_t)(t_ * kB + b0)) * 256 + w0_ + sc; \
    const unsigned* gw_ = xwt + ((size_t)(t_ * kB + b0)) * 256 + w0_ + sc; \
    const unsigned* gp_ = pt + ((size_t)(t_ * kP + p0)) * 256 + w0_ + sc; \
    S##x0 = *(const uint4*)(gx_ + (size_t)sr0 * 256); \
    S##x1 = *(const uint4*)(gx_ + (size_t)sr1 * 256); \
    S##w0 = *(const uint4*)(gw_ + (size_t)sr0 * 256); \
    S##w1 = *(const uint4*)(gw_ + (size_t)sr1 * 256); \
    S##p0 = *(const uint4*)(gp_ + (size_t)sr0 * 256); \
    S##p1 = *(const uint4*)(gp_ + (size_t)sr1 * 256); \
  } while (0)

#define STORE_LDS(S, CC) do { \
    unsigned* b_ = lds + ((CC) & 1) * BUF; \
    *(uint4*)(b_ + lw0) = S##x0; \
    *(uint4*)(b_ + lw1) = S##x1; \
    *(uint4*)(b_ + TSZ + lw0) = S##w0; \
    *(uint4*)(b_ + TSZ + lw1) = S##w1; \
    *(uint4*)(b_ + 2 * TSZ + lw0) = S##p0; \
    *(uint4*)(b_ + 2 * TSZ + lw1) = S##p1; \
  } while (0)

  auto compute = [&](int cc) {
    if ((cc & 3) == 0) {
      // issue norm loads for this t early (used 3 chunks later)
      const int t = tg * 7 + (cc >> 2);
      const int brow = b0 + wm * 16 + q * 4;
#pragma unroll
      for (int i = 0; i < 4; ++i) xnv[i] = xn[(brow + i) * 56 + t];
      pnv0 = pn[(p0 + wn * 32 + fr) * 56 + t];
      pnv1 = pn[(p0 + wn * 32 + 16 + fr) * 56 + t];
    }
    const unsigned* bx = lds + (cc & 1) * BUF;
    const unsigned* bw = bx + TSZ;
    const unsigned* bp = bx + 2 * TSZ;
#pragma unroll
    for (int ks = 0; ks < 4; ++ks) {
      const int col = (ks * 16 + q * 4) ^ sw;
      uint4 xr = *(const uint4*)(bx + axr + col);
      uint4 wr = *(const uint4*)(bw + axr + col);
      uint4 p0r = *(const uint4*)(bp + ap0r + col);
      uint4 p1r = *(const uint4*)(bp + ap1r + col);
      v8s xf = frag8(xr), wf = frag8(wr), pf0 = frag8(p0r), pf1 = frag8(p1r);
      aD0 = __builtin_amdgcn_mfma_f32_16x16x32_bf16(xf, pf0, aD0, 0, 0, 0);
      aD1 = __builtin_amdgcn_mfma_f32_16x16x32_bf16(xf, pf1, aD1, 0, 0, 0);
      aW0 = __builtin_amdgcn_mfma_f32_16x16x32_bf16(wf, pf0, aW0, 0, 0, 0);
      aW1 = __builtin_amdgcn_mfma_f32_16x16x32_bf16(wf, pf1, aW1, 0, 0, 0);
    }
    if ((cc & 3) == 3) {
      // end of one t: online softmax update
#pragma unroll
      for (int i = 0; i < 4; ++i) {
        {
          float den = fmaxf(xnv[i] * pnv0, 1e-8f);
          float sim = aD0[i] * __builtin_amdgcn_rcpf(den);
          float mo = m0v[i];
          float mn = fmaxf(mo, sim);
          float cs = __expf(mo - mn);
          float e = __expf(sim - mn);
          s0v[i] = s0v[i] * cs + e;
          n0v[i] = fmaf(e, aW0[i], n0v[i] * cs);
          m0v[i] = mn;
        }
        {
          float den = fmaxf(xnv[i] * pnv1, 1e-8f);
          float sim = aD1[i] * __builtin_amdgcn_rcpf(den);
          float mo = m1v[i];
          float mn = fmaxf(mo, sim);
          float cs = __expf(mo - mn);
          float e = __expf(sim - mn);
          s1v[i] = s1v[i] * cs + e;
          n1v[i] = fmaf(e, aW1[i], n1v[i] * cs);
          m1v[i] = mn;
        }
      }
      aD0 = aD1 = aW0 = aW1 = v4f{0.f, 0.f, 0.f, 0.f};
    }
  };

  // prologue: load(0)->A, store(0), load(1)->B
  LOAD_REGS(A, 0);
  STORE_LDS(A, 0);
  LOAD_REGS(B, 1);
  __syncthreads();

#pragma unroll 1
  for (int cc = 0; cc < 28; cc += 2) {
    // even half: store(cc+1) from B, prefetch(cc+2)->A, compute(cc)
    if (cc + 1 < 28) STORE_LDS(B, cc + 1);
    if (cc + 2 < 28) LOAD_REGS(A, cc + 2);
    compute(cc);
    __syncthreads();
    // odd half: store(cc+2) from A, prefetch(cc+3)->B, compute(cc+1)
    if (cc + 2 < 28) STORE_LDS(A, cc + 2);
    if (cc + 3 < 28) LOAD_REGS(B, cc + 3);
    compute(cc + 1);
    __syncthreads();
  }

#undef LOAD_REGS
#undef STORE_LDS

  // write partials: part[(tg*3 + comp)*131072 + b*512 + p]
  float* pm = part + ((size_t)tg * 3 + 0) * 131072;
  float* ps = part + ((size_t)tg * 3 + 1) * 131072;
  float* pu = part + ((size_t)tg * 3 + 2) * 131072;
#pragma unroll
  for (int i = 0; i < 4; ++i) {
    const int bg = b0 + wm * 16 + q * 4 + i;
    {
      const size_t o = (size_t)bg * 512 + p0 + wn * 32 + fr;
      pm[o] = m0v[i]; ps[o] = s0v[i]; pu[o] = n0v[i];
    }
    {
      const size_t o = (size_t)bg * 512 + p0 + wn * 32 + 16 + fr;
      pm[o] = m1v[i]; ps[o] = s1v[i]; pu[o] = n1v[i];
    }
  }
}

// ===========================================================================
// MERGE: combine the 8 t-group partials (log-sum-exp), + bias, relu.
// ===========================================================================
__global__ __launch_bounds__(256) void merge_kernel(
    const float* __restrict__ part, const float* __restrict__ fcb,
    float* __restrict__ out) {
  const int pair = blockIdx.x * 256 + threadIdx.x;
  float M = -3.0e38f;
#pragma unroll
  for (int k = 0; k < 8; ++k) M = fmaxf(M, part[((size_t)k * 3) * 131072 + pair]);
  float S = 0.f, N = 0.f;
#pragma unroll
  for (int k = 0; k < 8; ++k) {
    float mk = part[((size_t)k * 3) * 131072 + pair];
    float sc = __expf(mk - M);
    S = fmaf(part[((size_t)k * 3 + 1) * 131072 + pair], sc, S);
    N = fmaf(part[((size_t)k * 3 + 2) * 131072 + pair], sc, N);
  }
  float o = N * __builtin_amdgcn_rcpf(S) + fcb[0];
  out[pair] = fmaxf(o, 0.f);
}

// ===========================================================================
// FALLBACK (round-2 kernel, used only if ws_size is too small)
// ===========================================================================
__global__ __launch_bounds__(1024) void proto_mfma_kernel(
    const float* __restrict__ x, const float* __restrict__ proto,
    const float* __restrict__ fcw, const float* __restrict__ fcb,
    float* __restrict__ out) {
  __shared__ unsigned xs[56 * 289];
  __shared__ unsigned ps[56 * 145];
  __shared__ unsigned pws[56 * 145];

  const int tid = threadIdx.x;
  const int l = tid & 63;
  const int w = tid >> 6;
  const int bq = w & 1;
  const int tq = w >> 1;
  const int t0 = tq * 7;

  const int n = blockIdx.y * 32 + blockIdx.x;
  const int p0 = (n >> 3) * 16;
  const int b0 = (n & 7) * 32;

  const bool act = (l < 56);
  const int lt = l;

  const int xbase0 = ((b0 + 2 * w + 0) * kC) * kT + lt;
  const int xbase1 = ((b0 + 2 * w + 1) * kC) * kT + lt;
  const int pbase = ((p0 + w) * kC) * kT + lt;

  const int arow = l & 15;
  const int q2 = (l >> 4) << 1;
  const int xoff = (bq * 16 + arow) * 9 + q2;
  const int poff = arow * 9 + q2;

  v4f acc[7][2];
#pragma unroll
  for (int ti = 0; ti < 7; ++ti) {
    acc[ti][0] = v4f{0.f, 0.f, 0.f, 0.f};
    acc[ti][1] = v4f{0.f, 0.f, 0.f, 0.f};
  }
  float xn2a = 0.f, xn2b = 0.f, pn2 = 0.f;

#pragma unroll 1
  for (int st = 0; st < 32; ++st) {
    const int k0 = st * 16;
    if (act) {
#pragma unroll
      for (int r = 0; r < 16; ++r) {
        const int cw = r & 7;
        const int c = k0 + 2 * cw;
        const int ga = ((r >> 3) ? xbase1 : xbase0) + c * kT;
        float g0 = x[ga], g1 = x[ga + kT];
        if (r >> 3) xn2b = fmaf(g0, g0, fmaf(g1, g1, xn2b));
        else xn2a = fmaf(g0, g0, fmaf(g1, g1, xn2a));
        xs[lt * 289 + (2 * w + (r >> 3)) * 9 + cw] = pack_bf16(g0, g1);
      }
#pragma unroll
      for (int cw = 0; cw < 8; ++cw) {
        const int c = k0 + 2 * cw;
        const int ga = pbase + c * kT;
        float g0 = proto[ga], g1 = proto[ga + kT];
        pn2 = fmaf(g0, g0, fmaf(g1, g1, pn2));
        ps[lt * 145 + w * 9 + cw] = pack_bf16(g0, g1);
        float f0 = fcw[c], f1 = fcw[c + 1];
        pws[lt * 145 + w * 9 + cw] = pack_bf16(g0 * f0, g1 * f1);
      }
    }
    __syncthreads();
#pragma unroll
    for (int ti = 0; ti < 7; ++ti) {
      const int t = t0 + ti;
      unsigned xw0 = xs[t * 289 + xoff];
      unsigned xw1 = xs[t * 289 + xoff + 1];
      unsigned pw0 = ps[t * 145 + poff];
      unsigned pw1 = ps[t * 145 + poff + 1];
      unsigned ww0 = pws[t * 145 + poff];
      unsigned ww1 = pws[t * 145 + poff + 1];
      v4s af = frag2(xw0, xw1);
      v4s bf = frag2(pw0, pw1);
      v4s wf = frag2(ww0, ww1);
      acc[ti][0] = __builtin_amdgcn_mfma_f32_16x16x16bf16_1k(af, bf, acc[ti][0], 0, 0, 0);
      acc[ti][1] = __builtin_amdgcn_mfma_f32_16x16x16bf16_1k(af, wf, acc[ti][1], 0, 0, 0);
    }
    __syncthreads();
  }

  float* xnorm = (float*)ps;
  float* pnorm = xnorm + 32 * 56;
  if (act) {
    xnorm[(2 * w + 0) * 56 + lt] = xn2a;
    xnorm[(2 * w + 1) * 56 + lt] = xn2b;
    pnorm[w * 56 + lt] = pn2;
  }
  __syncthreads();

  float* fm = (float*)xs;
  float* fsum = fm + 4096;
  float* fnum = fsum + 4096;
  const int pc = arow;
  const int qq = l >> 4;
#pragma unroll
  for (int i = 0; i < 4; ++i) {
    const int bl = bq * 16 + 4 * qq + i;
    float m = -3.0e38f;
    float sims[7];
#pragma unroll
    for (int ti = 0; ti < 7; ++ti) {
      const int t = t0 + ti;
      float den = fmaxf(sqrtf(xnorm[bl * 56 + t]) * sqrtf(pnorm[pc * 56 + t]), 1e-8f);
      float s = acc[ti][0][i] / den;
      sims[ti] = s;
      m = fmaxf(m, s);
    }
    float se = 0.f, nu = 0.f;
#pragma unroll
    for (int ti = 0; ti < 7; ++ti) {
      float e = __expf(sims[ti] - m);
      se += e;
      nu = fmaf(e, acc[ti][1][i], nu);
    }
    const int pair = bl * 16 + pc;
    fm[tq * 512 + pair] = m;
    fsum[tq * 512 + pair] = se;
    fnum[tq * 512 + pair] = nu;
  }
  __syncthreads();

  if (tid < 512) {
    float M = -3.0e38f;
#pragma unroll
    for (int k = 0; k < 8; ++k) M = fmaxf(M, fm[k * 512 + tid]);
    float S = 0.f, N = 0.f;
#pragma unroll
    for (int k = 0; k < 8; ++k) {
      float sc = __expf(fm[k * 512 + tid] - M);
      S = fmaf(fsum[k * 512 + tid], sc, S);
      N = fmaf(fnum[k * 512 + tid], sc, N);
    }
    float o = N / S + fcb[0];
    out[(b0 + (tid >> 4)) * kP + p0 + (tid & 15)] = fmaxf(o, 0.f);
  }
}

// ===========================================================================
extern "C" void kernel_launch(void* const* d_in, const int* in_sizes, int n_in,
                              void* d_out, int out_size, void* d_ws, size_t ws_size,
                              hipStream_t stream) {
  const float* x = (const float*)d_in[0];
  const float* proto = (const float*)d_in[1];
  const float* fcw = (const float*)d_in[2];
  const float* fcb = (const float*)d_in[3];
  float* out = (float*)d_out;

  // ws layout (words): xt 3,670,016 | xwt 3,670,016 | pt 7,340,032 |
  // part 3,145,728 | xn 14,336 | pn 28,672  => 17,868,800 words = 71,475,200 B
  const size_t need = 71475200;
  if (ws_size >= need) {
    unsigned* xt = (unsigned*)d_ws;
    unsigned* xwt = xt + 3670016;
    unsigned* ptb = xt + 7340032;
    float* partb = (float*)(xt + 14680064);
    float* xnb = (float*)(xt + 17825792);
    float* pnb = (float*)(xt + 17840128);

    hipLaunchKernelGGL(prep_kernel, dim3(kB + kP), dim3(512), 0, stream,
                       x, proto, fcw, xt, xwt, ptb, xnb, pnb);
    hipLaunchKernelGGL(proto_gemm_kernel, dim3(4, 8, 8), dim3(512), 0, stream,
                       xt, xwt, ptb, xnb, pnb, partb);
    hipLaunchKernelGGL(merge_kernel, dim3(512), dim3(256), 0, stream,
                       partb, fcb, out);
  } else {
    hipLaunchKernelGGL(proto_mfma_kernel, dim3(32, 8), dim3(1024), 0, stream,
                       x, proto, fcw, fcb, out);
  }
}

// Round 5
// 65.269 us; speedup vs baseline: 6.0455x; 1.1267x over previous
//
#include <hip/hip_runtime.h>
#include <hip/hip_bf16.h>
#include <math.h>

// Problem constants
constexpr int kB = 256, kC = 512, kT = 56, kP = 512;
constexpr int kCT = kC * kT;  // 28672 floats per row

typedef short v4s __attribute__((ext_vector_type(4)));
typedef short v8s __attribute__((ext_vector_type(8)));
typedef float v4f __attribute__((ext_vector_type(4)));

__device__ __forceinline__ unsigned pack_bf16(float a, float b) {
  __hip_bfloat16 ha = __float2bfloat16(a);
  __hip_bfloat16 hb = __float2bfloat16(b);
  unsigned short ua, ub;
  __builtin_memcpy(&ua, &ha, 2);
  __builtin_memcpy(&ub, &hb, 2);
  return (unsigned)ua | ((unsigned)ub << 16);
}

__device__ __forceinline__ v4s frag2(unsigned w0, unsigned w1) {
  unsigned u[2] = {w0, w1};
  v4s s;
  __builtin_memcpy(&s, u, 8);
  return s;
}

__device__ __forceinline__ v8s frag8(uint4 u) {
  v8s s;
  __builtin_memcpy(&s, &u, 16);
  return s;
}

// ===========================================================================
// PREP v2: per source row, process c in 4 chunks of 128 (LDS 33 KB -> 3
// resident blocks/CU = 24 waves, vs 1 block/8 waves before). Per chunk:
// stage [128 c][56 t] fp32 (coalesced float4), transpose-scatter to LDS
// (stride 57: pack-phase reads hit 16 distinct banks / 16-lane group),
// accumulate norm partials in registers, pack bf16 words + write coalesced.
// ===========================================================================
__global__ __launch_bounds__(512) void prep_kernel(
    const float* __restrict__ x, const float* __restrict__ proto,
    const float* __restrict__ fcw,
    unsigned* __restrict__ xt, unsigned* __restrict__ xwt,
    unsigned* __restrict__ pt,
    float* __restrict__ xn, float* __restrict__ pn) {
  __shared__ float tile[128 * 57];  // 29,184 B
  __shared__ float fws[512];
  __shared__ float part[8][64];

  const int tid = threadIdx.x;
  const int n = blockIdx.x;
  const bool isx = (n < kB);
  const int row = isx ? n : (n - kB);
  const float* src = (isx ? x : proto) + (size_t)row * kCT;

  fws[tid] = fcw[tid & 511];

  const int g = tid >> 6, tt = tid & 63;
  float nacc = 0.f;

#pragma unroll 1
  for (int ch = 0; ch < 4; ++ch) {
    const float* csrc = src + ch * (128 * 56);
    // stage chunk: 1792 float4 (coalesced), scatter-transpose to tile[c][t]
#pragma unroll
    for (int it = 0; it < 4; ++it) {
      const int idx = it * 512 + tid;
      if (idx < 1792) {
        const int f0 = idx * 4;
        float4 v = *(const float4*)(csrc + f0);
        int c = (int)(((unsigned)f0 * 74899u) >> 22);  // f0 / 56
        int t = f0 - c * 56;  // multiple of 4; 56%4==0 so no row crossing
        tile[c * 57 + t] = v.x;
        tile[c * 57 + t + 1] = v.y;
        tile[c * 57 + t + 2] = v.z;
        tile[c * 57 + t + 3] = v.w;
      }
    }
    __syncthreads();
    // norm partials: group g covers c-sub [g*16, g*16+16) of this chunk
    if (tt < 56) {
#pragma unroll
      for (int cc2 = 0; cc2 < 16; ++cc2) {
        float u = tile[(g * 16 + cc2) * 57 + tt];
        nacc = fmaf(u, u, nacc);
      }
    }
    // pack + coalesced global write: 3584 words (56 t x 64 cw)
#pragma unroll
    for (int it = 0; it < 7; ++it) {
      const int id = it * 512 + tid;
      const int t = id >> 6;
      const int cw = id & 63;
      float g0 = tile[(2 * cw) * 57 + t];
      float g1 = tile[(2 * cw + 1) * 57 + t];
      unsigned wd = pack_bf16(g0, g1);
      if (isx) {
        size_t o = ((size_t)(t * kB + row)) * 256 + ch * 64 + cw;
        xt[o] = wd;
        const int c = ch * 128 + 2 * cw;
        xwt[o] = pack_bf16(g0 * fws[c], g1 * fws[c + 1]);
      } else {
        pt[((size_t)(t * kP + row)) * 256 + ch * 64 + cw] = wd;
      }
    }
    __syncthreads();
  }

  part[g][tt] = nacc;
  __syncthreads();
  if (tid < 56) {
    float s = 0.f;
#pragma unroll
    for (int gg = 0; gg < 8; ++gg) s += part[gg][tid];
    float r = sqrtf(s);
    if (isx) xn[row * 56 + tid] = r; else pn[row * 56 + tid] = r;
  }
}

// ===========================================================================
// MAIN (unchanged from r4): block = 64b x 64p x 7t, 8 waves of 16b x 32p,
// mfma_f32_16x16x32_bf16, XOR-swizzled LDS, single barrier per chunk with
// 2-deep named reg sets.
// ===========================================================================
constexpr int TSZ = 64 * 64;   // one tile: 4096 words (16 KB)
constexpr int BUF = 3 * TSZ;   // x + xw + p per buffer: 12288 words

__global__ __launch_bounds__(512) void proto_gemm_kernel(
    const unsigned* __restrict__ xt, const unsigned* __restrict__ xwt,
    const unsigned* __restrict__ pt,
    const float* __restrict__ xn, const float* __restrict__ pn,
    float* __restrict__ part) {
  __shared__ __align__(16) unsigned lds[2 * BUF];  // 98,304 B

  const int tid = threadIdx.x;
  const int l = tid & 63;
  const int w = tid >> 6;
  const int wm = w & 3;
  const int wn = w >> 2;
  const int b0 = blockIdx.x * 64;
  const int p0 = blockIdx.y * 64;
  const int tg = blockIdx.z;

  const int sr0 = tid >> 4;
  const int sr1 = sr0 + 32;
  const int sc = (tid & 15) * 4;
  const int lw0 = sr0 * 64 + (sc ^ ((sr0 & 7) * 4));
  const int lw1 = sr1 * 64 + (sc ^ ((sr1 & 7) * 4));

  const int fr = l & 15;
  const int q = l >> 4;
  const int sw = (fr & 7) * 4;
  const int axr = (wm * 16 + fr) * 64;
  const int ap0r = (wn * 32 + fr) * 64;
  const int ap1r = ap0r + 16 * 64;

  v4f aD0, aD1, aW0, aW1;
  aD0 = aD1 = aW0 = aW1 = v4f{0.f, 0.f, 0.f, 0.f};
  v4f m0v, m1v, s0v, s1v, n0v, n1v;
  m0v = m1v = v4f{-3.0e38f, -3.0e38f, -3.0e38f, -3.0e38f};
  s0v = s1v = n0v = n1v = v4f{0.f, 0.f, 0.f, 0.f};

  uint4 Ax0, Ax1, Aw0, Aw1, Ap0, Ap1;
  uint4 Bx0, Bx1, Bw0, Bw1, Bp0, Bp1;
  float xnv[4] = {0.f, 0.f, 0.f, 0.f};
  float pnv0 = 0.f, pnv1 = 0.f;

#define LOAD_REGS(S, CC) do { \
    const int t_ = tg * 7 + ((CC) >> 2); \
    const int w0_ = ((CC) & 3) * 64; \
    const unsigned* gx_ = xt + ((size_t)(t_ * kB + b0)) * 256 + w0_ + sc; \
    const unsigned* gw_ = xwt + ((size_t)(t_ * kB + b0)) * 256 + w0_ + sc; \
    const unsigned* gp_ = pt + ((size_t)(t_ * kP + p0)) * 256 + w0_ + sc; \
    S##x0 = *(const uint4*)(gx_ + (size_t)sr0 * 256); \
    S##x1 = *(const uint4*)(gx_ + (size_t)sr1 * 256); \
    S##w0 = *(const uint4*)(gw_ + (size_t)sr0 * 256); \
    S##w1 = *(const uint4*)(gw_ + (size_t)sr1 * 256); \
    S##p0 = *(const uint4*)(gp_ + (size_t)sr0 * 256); \
    S##p1 = *(const uint4*)(gp_ + (size_t)sr1 * 256); \
  } while (0)

#define STORE_LDS(S, CC) do { \
    unsigned* b_ = lds + ((CC) & 1) * BUF; \
    *(uint4*)(b_ + lw0) = S##x0; \
    *(uint4*)(b_ + lw1) = S##x1; \
    *(uint4*)(b_ + TSZ + lw0) = S##w0; \
    *(uint4*)(b_ + TSZ + lw1) = S##w1; \
    *(uint4*)(b_ + 2 * TSZ + lw0) = S##p0; \
    *(uint4*)(b_ + 2 * TSZ + lw1) = S##p1; \
  } while (0)

  auto compute = [&](int cc) {
    if ((cc & 3) == 0) {
      const int t = tg * 7 + (cc >> 2);
      const int brow = b0 + wm * 16 + q * 4;
#pragma unroll
      for (int i = 0; i < 4; ++i) xnv[i] = xn[(brow + i) * 56 + t];
      pnv0 = pn[(p0 + wn * 32 + fr) * 56 + t];
      pnv1 = pn[(p0 + wn * 32 + 16 + fr) * 56 + t];
    }
    const unsigned* bx = lds + (cc & 1) * BUF;
    const unsigned* bw = bx + TSZ;
    const unsigned* bp = bx + 2 * TSZ;
#pragma unroll
    for (int ks = 0; ks < 4; ++ks) {
      const int col = (ks * 16 + q * 4) ^ sw;
      uint4 xr = *(const uint4*)(bx + axr + col);
      uint4 wr = *(const uint4*)(bw + axr + col);
      uint4 p0r = *(const uint4*)(bp + ap0r + col);
      uint4 p1r = *(const uint4*)(bp + ap1r + col);
      v8s xf = frag8(xr), wf = frag8(wr), pf0 = frag8(p0r), pf1 = frag8(p1r);
      aD0 = __builtin_amdgcn_mfma_f32_16x16x32_bf16(xf, pf0, aD0, 0, 0, 0);
      aD1 = __builtin_amdgcn_mfma_f32_16x16x32_bf16(xf, pf1, aD1, 0, 0, 0);
      aW0 = __builtin_amdgcn_mfma_f32_16x16x32_bf16(wf, pf0, aW0, 0, 0, 0);
      aW1 = __builtin_amdgcn_mfma_f32_16x16x32_bf16(wf, pf1, aW1, 0, 0, 0);
    }
    if ((cc & 3) == 3) {
#pragma unroll
      for (int i = 0; i < 4; ++i) {
        {
          float den = fmaxf(xnv[i] * pnv0, 1e-8f);
          float sim = aD0[i] * __builtin_amdgcn_rcpf(den);
          float mo = m0v[i];
          float mn = fmaxf(mo, sim);
          float cs = __expf(mo - mn);
          float e = __expf(sim - mn);
          s0v[i] = s0v[i] * cs + e;
          n0v[i] = fmaf(e, aW0[i], n0v[i] * cs);
          m0v[i] = mn;
        }
        {
          float den = fmaxf(xnv[i] * pnv1, 1e-8f);
          float sim = aD1[i] * __builtin_amdgcn_rcpf(den);
          float mo = m1v[i];
          float mn = fmaxf(mo, sim);
          float cs = __expf(mo - mn);
          float e = __expf(sim - mn);
          s1v[i] = s1v[i] * cs + e;
          n1v[i] = fmaf(e, aW1[i], n1v[i] * cs);
          m1v[i] = mn;
        }
      }
      aD0 = aD1 = aW0 = aW1 = v4f{0.f, 0.f, 0.f, 0.f};
    }
  };

  LOAD_REGS(A, 0);
  STORE_LDS(A, 0);
  LOAD_REGS(B, 1);
  __syncthreads();

#pragma unroll 1
  for (int cc = 0; cc < 28; cc += 2) {
    if (cc + 1 < 28) STORE_LDS(B, cc + 1);
    if (cc + 2 < 28) LOAD_REGS(A, cc + 2);
    compute(cc);
    __syncthreads();
    if (cc + 2 < 28) STORE_LDS(A, cc + 2);
    if (cc + 3 < 28) LOAD_REGS(B, cc + 3);
    compute(cc + 1);
    __syncthreads();
  }

#undef LOAD_REGS
#undef STORE_LDS

  float* pm = part + ((size_t)tg * 3 + 0) * 131072;
  float* ps = part + ((size_t)tg * 3 + 1) * 131072;
  float* pu = part + ((size_t)tg * 3 + 2) * 131072;
#pragma unroll
  for (int i = 0; i < 4; ++i) {
    const int bg = b0 + wm * 16 + q * 4 + i;
    {
      const size_t o = (size_t)bg * 512 + p0 + wn * 32 + fr;
      pm[o] = m0v[i]; ps[o] = s0v[i]; pu[o] = n0v[i];
    }
    {
      const size_t o = (size_t)bg * 512 + p0 + wn * 32 + 16 + fr;
      pm[o] = m1v[i]; ps[o] = s1v[i]; pu[o] = n1v[i];
    }
  }
}

// ===========================================================================
// MERGE: combine the 8 t-group partials (log-sum-exp), + bias, relu.
// ===========================================================================
__global__ __launch_bounds__(256) void merge_kernel(
    const float* __restrict__ part, const float* __restrict__ fcb,
    float* __restrict__ out) {
  const int pair = blockIdx.x * 256 + threadIdx.x;
  float M = -3.0e38f;
#pragma unroll
  for (int k = 0; k < 8; ++k) M = fmaxf(M, part[((size_t)k * 3) * 131072 + pair]);
  float S = 0.f, N = 0.f;
#pragma unroll
  for (int k = 0; k < 8; ++k) {
    float mk = part[((size_t)k * 3) * 131072 + pair];
    float sc = __expf(mk - M);
    S = fmaf(part[((size_t)k * 3 + 1) * 131072 + pair], sc, S);
    N = fmaf(part[((size_t)k * 3 + 2) * 131072 + pair], sc, N);
  }
  float o = N * __builtin_amdgcn_rcpf(S) + fcb[0];
  out[pair] = fmaxf(o, 0.f);
}

// ===========================================================================
// FALLBACK (round-2 kernel, used only if ws_size is too small)
// ===========================================================================
__global__ __launch_bounds__(1024) void proto_mfma_kernel(
    const float* __restrict__ x, const float* __restrict__ proto,
    const float* __restrict__ fcw, const float* __restrict__ fcb,
    float* __restrict__ out) {
  __shared__ unsigned xs[56 * 289];
  __shared__ unsigned ps[56 * 145];
  __shared__ unsigned pws[56 * 145];

  const int tid = threadIdx.x;
  const int l = tid & 63;
  const int w = tid >> 6;
  const int bq = w & 1;
  const int tq = w >> 1;
  const int t0 = tq * 7;

  const int n = blockIdx.y * 32 + blockIdx.x;
  const int p0 = (n >> 3) * 16;
  const int b0 = (n & 7) * 32;

  const bool act = (l < 56);
  const int lt = l;

  const int xbase0 = ((b0 + 2 * w + 0) * kC) * kT + lt;
  const int xbase1 = ((b0 + 2 * w + 1) * kC) * kT + lt;
  const int pbase = ((p0 + w) * kC) * kT + lt;

  const int arow = l & 15;
  const int q2 = (l >> 4) << 1;
  const int xoff = (bq * 16 + arow) * 9 + q2;
  const int poff = arow * 9 + q2;

  v4f acc[7][2];
#pragma unroll
  for (int ti = 0; ti < 7; ++ti) {
    acc[ti][0] = v4f{0.f, 0.f, 0.f, 0.f};
    acc[ti][1] = v4f{0.f, 0.f, 0.f, 0.f};
  }
  float xn2a = 0.f, xn2b = 0.f, pn2 = 0.f;

#pragma unroll 1
  for (int st = 0; st < 32; ++st) {
    const int k0 = st * 16;
    if (act) {
#pragma unroll
      for (int r = 0; r < 16; ++r) {
        const int cw = r & 7;
        const int c = k0 + 2 * cw;
        const int ga = ((r >> 3) ? xbase1 : xbase0) + c * kT;
        float g0 = x[ga], g1 = x[ga + kT];
        if (r >> 3) xn2b = fmaf(g0, g0, fmaf(g1, g1, xn2b));
        else xn2a = fmaf(g0, g0, fmaf(g1, g1, xn2a));
        xs[lt * 289 + (2 * w + (r >> 3)) * 9 + cw] = pack_bf16(g0, g1);
      }
#pragma unroll
      for (int cw = 0; cw < 8; ++cw) {
        const int c = k0 + 2 * cw;
        const int ga = pbase + c * kT;
        float g0 = proto[ga], g1 = proto[ga + kT];
        pn2 = fmaf(g0, g0, fmaf(g1, g1, pn2));
        ps[lt * 145 + w * 9 + cw] = pack_bf16(g0, g1);
        float f0 = fcw[c], f1 = fcw[c + 1];
        pws[lt * 145 + w * 9 + cw] = pack_bf16(g0 * f0, g1 * f1);
      }
    }
    __syncthreads();
#pragma unroll
    for (int ti = 0; ti < 7; ++ti) {
      const int t = t0 + ti;
      unsigned xw0 = xs[t * 289 + xoff];
      unsigned xw1 = xs[t * 289 + xoff + 1];
      unsigned pw0 = ps[t * 145 + poff];
      unsigned pw1 = ps[t * 145 + poff + 1];
      unsigned ww0 = pws[t * 145 + poff];
      unsigned ww1 = pws[t * 145 + poff + 1];
      v4s af = frag2(xw0, xw1);
      v4s bf = frag2(pw0, pw1);
      v4s wf = frag2(ww0, ww1);
      acc[ti][0] = __builtin_amdgcn_mfma_f32_16x16x16bf16_1k(af, bf, acc[ti][0], 0, 0, 0);
      acc[ti][1] = __builtin_amdgcn_mfma_f32_16x16x16bf16_1k(af, wf, acc[ti][1], 0, 0, 0);
    }
    __syncthreads();
  }

  float* xnorm = (float*)ps;
  float* pnorm = xnorm + 32 * 56;
  if (act) {
    xnorm[(2 * w + 0) * 56 + lt] = xn2a;
    xnorm[(2 * w + 1) * 56 + lt] = xn2b;
    pnorm[w * 56 + lt] = pn2;
  }
  __syncthreads();

  float* fm = (float*)xs;
  float* fsum = fm + 4096;
  float* fnum = fsum + 4096;
  const int pc = arow;
  const int qq = l >> 4;
#pragma unroll
  for (int i = 0; i < 4; ++i) {
    const int bl = bq * 16 + 4 * qq + i;
    float m = -3.0e38f;
    float sims[7];
#pragma unroll
    for (int ti = 0; ti < 7; ++ti) {
      const int t = t0 + ti;
      float den = fmaxf(sqrtf(xnorm[bl * 56 + t]) * sqrtf(pnorm[pc * 56 + t]), 1e-8f);
      float s = acc[ti][0][i] / den;
      sims[ti] = s;
      m = fmaxf(m, s);
    }
    float se = 0.f, nu = 0.f;
#pragma unroll
    for (int ti = 0; ti < 7; ++ti) {
      float e = __expf(sims[ti] - m);
      se += e;
      nu = fmaf(e, acc[ti][1][i], nu);
    }
    const int pair = bl * 16 + pc;
    fm[tq * 512 + pair] = m;
    fsum[tq * 512 + pair] = se;
    fnum[tq * 512 + pair] = nu;
  }
  __syncthreads();

  if (tid < 512) {
    float M = -3.0e38f;
#pragma unroll
    for (int k = 0; k < 8; ++k) M = fmaxf(M, fm[k * 512 + tid]);
    float S = 0.f, N = 0.f;
#pragma unroll
    for (int k = 0; k < 8; ++k) {
      float sc = __expf(fm[k * 512 + tid] - M);
      S = fmaf(fsum[k * 512 + tid], sc, S);
      N = fmaf(fnum[k * 512 + tid], sc, N);
    }
    float o = N / S + fcb[0];
    out[(b0 + (tid >> 4)) * kP + p0 + (tid & 15)] = fmaxf(o, 0.f);
  }
}

// ===========================================================================
extern "C" void kernel_launch(void* const* d_in, const int* in_sizes, int n_in,
                              void* d_out, int out_size, void* d_ws, size_t ws_size,
                              hipStream_t stream) {
  const float* x = (const float*)d_in[0];
  const float* proto = (const float*)d_in[1];
  const float* fcw = (const float*)d_in[2];
  const float* fcb = (const float*)d_in[3];
  float* out = (float*)d_out;

  // ws layout (words): xt 3,670,016 | xwt 3,670,016 | pt 7,340,032 |
  // part 3,145,728 | xn 14,336 | pn 28,672  => 17,868,800 words = 71,475,200 B
  const size_t need = 71475200;
  if (ws_size >= need) {
    unsigned* xt = (unsigned*)d_ws;
    unsigned* xwt = xt + 3670016;
    unsigned* ptb = xt + 7340032;
    float* partb = (float*)(xt + 14680064);
    float* xnb = (float*)(xt + 17825792);
    float* pnb = (float*)(xt + 17840128);

    hipLaunchKernelGGL(prep_kernel, dim3(kB + kP), dim3(512), 0, stream,
                       x, proto, fcw, xt, xwt, ptb, xnb, pnb);
    hipLaunchKernelGGL(proto_gemm_kernel, dim3(4, 8, 8), dim3(512), 0, stream,
                       xt, xwt, ptb, xnb, pnb, partb);
    hipLaunchKernelGGL(merge_kernel, dim3(512), dim3(256), 0, stream,
                       partb, fcb, out);
  } else {
    hipLaunchKernelGGL(proto_mfma_kernel, dim3(32, 8), dim3(1024), 0, stream,
                       x, proto, fcw, fcb, out);
  }
}

// Round 6
// 62.381 us; speedup vs baseline: 6.3254x; 1.0463x over previous
//
#include <hip/hip_runtime.h>
#include <hip/hip_bf16.h>
#include <math.h>

// Problem constants
constexpr int kB = 256, kC = 512, kT = 56, kP = 512;
constexpr int kCT = kC * kT;  // 28672 floats per row

typedef short v4s __attribute__((ext_vector_type(4)));
typedef short v8s __attribute__((ext_vector_type(8)));
typedef float v4f __attribute__((ext_vector_type(4)));
typedef float v16f __attribute__((ext_vector_type(16)));

__device__ __forceinline__ unsigned pack_bf16(float a, float b) {
  __hip_bfloat16 ha = __float2bfloat16(a);
  __hip_bfloat16 hb = __float2bfloat16(b);
  unsigned short ua, ub;
  __builtin_memcpy(&ua, &ha, 2);
  __builtin_memcpy(&ub, &hb, 2);
  return (unsigned)ua | ((unsigned)ub << 16);
}

__device__ __forceinline__ v4s frag2(unsigned w0, unsigned w1) {
  unsigned u[2] = {w0, w1};
  v4s s;
  __builtin_memcpy(&s, u, 8);
  return s;
}

__device__ __forceinline__ v8s frag8(uint4 u) {
  v8s s;
  __builtin_memcpy(&s, &u, 16);
  return s;
}

// bf16 unpack halves to f32
__device__ __forceinline__ float bfl(unsigned u) {
  unsigned v = u << 16;
  float f;
  __builtin_memcpy(&f, &v, 4);
  return f;
}
__device__ __forceinline__ float bfh(unsigned u) {
  unsigned v = u & 0xffff0000u;
  float f;
  __builtin_memcpy(&f, &v, 4);
  return f;
}
// pack two f32 -> bf16x2 word (RNE), lo = s0
__device__ __forceinline__ unsigned cvtpk(float lo, float hi) {
  unsigned r;
  asm("v_cvt_pk_bf16_f32 %0, %1, %2" : "=v"(r) : "v"(lo), "v"(hi));
  return r;
}

// ===========================================================================
// PREP v3: per source row, 4 chunks of 128 c; stage fp32 (coalesced),
// transpose via LDS, pack bf16 t-major words (xt / pt only — xwt removed,
// fc-fold now happens in-register inside the gemm), fused norms.
// ===========================================================================
__global__ __launch_bounds__(512) void prep_kernel(
    const float* __restrict__ x, const float* __restrict__ proto,
    unsigned* __restrict__ xt, unsigned* __restrict__ pt,
    float* __restrict__ xn, float* __restrict__ pn) {
  __shared__ float tile[128 * 57];  // 29,184 B
  __shared__ float part[8][64];

  const int tid = threadIdx.x;
  const int n = blockIdx.x;
  const bool isx = (n < kB);
  const int row = isx ? n : (n - kB);
  const float* src = (isx ? x : proto) + (size_t)row * kCT;

  const int g = tid >> 6, tt = tid & 63;
  float nacc = 0.f;

#pragma unroll 1
  for (int ch = 0; ch < 4; ++ch) {
    const float* csrc = src + ch * (128 * 56);
#pragma unroll
    for (int it = 0; it < 4; ++it) {
      const int idx = it * 512 + tid;
      if (idx < 1792) {
        const int f0 = idx * 4;
        float4 v = *(const float4*)(csrc + f0);
        int c = (int)(((unsigned)f0 * 74899u) >> 22);  // f0 / 56
        int t = f0 - c * 56;  // 56%4==0 -> no row crossing
        tile[c * 57 + t] = v.x;
        tile[c * 57 + t + 1] = v.y;
        tile[c * 57 + t + 2] = v.z;
        tile[c * 57 + t + 3] = v.w;
      }
    }
    __syncthreads();
    if (tt < 56) {
#pragma unroll
      for (int cc2 = 0; cc2 < 16; ++cc2) {
        float u = tile[(g * 16 + cc2) * 57 + tt];
        nacc = fmaf(u, u, nacc);
      }
    }
#pragma unroll
    for (int it = 0; it < 7; ++it) {
      const int id = it * 512 + tid;
      const int t = id >> 6;
      const int cw = id & 63;
      float g0 = tile[(2 * cw) * 57 + t];
      float g1 = tile[(2 * cw + 1) * 57 + t];
      unsigned wd = pack_bf16(g0, g1);
      if (isx)
        xt[((size_t)(t * kB + row)) * 256 + ch * 64 + cw] = wd;
      else
        pt[((size_t)(t * kP + row)) * 256 + ch * 64 + cw] = wd;
    }
    __syncthreads();
  }

  part[g][tt] = nacc;
  __syncthreads();
  if (tid < 56) {
    float s = 0.f;
#pragma unroll
    for (int gg = 0; gg < 8; ++gg) s += part[gg][tid];
    float r = sqrtf(s);
    if (isx) xn[row * 56 + tid] = r; else pn[row * 56 + tid] = r;
  }
}

// ===========================================================================
// MAIN v3: mfma_f32_32x32x16_bf16, wave tile 32b x 32p, block 64b x 64p x 4t
// (4 waves, 256 thr), grid 4 x 8 x 14 = 448, K-chunk 32 words (64 c).
// LDS: x / xw / p tiles 64x32w, double-buffered = 48 KB -> 3 blocks/CU.
// xw computed in-register at staging time (x_bf16 * fcw_f32 -> cvt_pk_bf16).
// No-max online softmax: |sim|<=1 so exp is bounded; state = (s, n) only.
// XOR swizzle col ^= (row&7)*4 keeps both ds_write_b128 and frag reads 2-way.
// ===========================================================================
constexpr int CW = 32;           // chunk words (=64 c)
constexpr int TILE = 64 * CW;    // 2048 words
constexpr int BUFW = 3 * TILE;   // x + xw + p = 6144 words

__global__ __launch_bounds__(256, 3) void proto_gemm_kernel(
    const unsigned* __restrict__ xt, const unsigned* __restrict__ pt,
    const float* __restrict__ fcw,
    const float* __restrict__ xn, const float* __restrict__ pn,
    float* __restrict__ part) {
  __shared__ __align__(16) unsigned lds[2 * BUFW];  // 49,152 B

  const int tid = threadIdx.x;
  const int l = tid & 63;
  const int w = tid >> 6;     // wave 0..3
  const int wm = w >> 1;      // b half
  const int wn = w & 1;       // p half
  const int b0 = blockIdx.x * 64;
  const int p0 = blockIdx.y * 64;
  const int tg = blockIdx.z;  // t = tg*4 .. tg*4+3

  // staging: ids {tid, tid+256}: row = id>>3 (8 thr/row), colw = (tid&7)*4
  const int srow = tid >> 3;           // 0..31
  const int scolw = (tid & 7) * 4;
  const int ssw = (srow & 7) * 4;      // same for srow and srow+32
  const int lwA = srow * CW + (scolw ^ ssw);
  const int lwB = (srow + 32) * CW + (scolw ^ ssw);

  // fragment geometry (32x32x16: lane -> row l&31, k-half l>>5)
  const int fr = l & 31;
  const int hi = l >> 5;
  const int sw4 = (l & 7) * 4;
  const int axb = (wm * 32 + fr) * CW;  // x/xw row base (words)
  const int pxb = (wn * 32 + fr) * CW;  // p row base

  v16f aD, aW, sac, nac;
#pragma unroll
  for (int i = 0; i < 16; ++i) { aD[i] = 0.f; aW[i] = 0.f; sac[i] = 0.f; nac[i] = 0.f; }

  uint4 Ax0, Ax1, Ap0, Ap1;
  float4 Af0, Af1;
  uint4 Bx0, Bx1, Bp0, Bp1;
  float4 Bf0, Bf1;

#define LOAD_REGS(S, CC) do { \
    const int t_ = tg * 4 + ((CC) >> 3); \
    const int ch_ = (CC) & 7; \
    const unsigned* gx_ = xt + ((size_t)(t_ * kB + b0 + srow)) * 256 + ch_ * CW + scolw; \
    const unsigned* gp_ = pt + ((size_t)(t_ * kP + p0 + srow)) * 256 + ch_ * CW + scolw; \
    S##x0 = *(const uint4*)(gx_); \
    S##x1 = *(const uint4*)(gx_ + 32 * 256); \
    S##p0 = *(const uint4*)(gp_); \
    S##p1 = *(const uint4*)(gp_ + 32 * 256); \
    const float* gf_ = fcw + ch_ * 64 + (tid & 7) * 8; \
    S##f0 = *(const float4*)(gf_); \
    S##f1 = *(const float4*)(gf_ + 4); \
  } while (0)

  // xw word: per bf16 pair multiply by fp32 fcw, repack (RNE)
#define WMUL(xv, fa, fb, out) do { \
    out.x = cvtpk(bfl(xv.x) * fa.x, bfh(xv.x) * fa.y); \
    out.y = cvtpk(bfl(xv.y) * fa.z, bfh(xv.y) * fa.w); \
    out.z = cvtpk(bfl(xv.z) * fb.x, bfh(xv.z) * fb.y); \
    out.w = cvtpk(bfl(xv.w) * fb.z, bfh(xv.w) * fb.w); \
  } while (0)

#define STORE_LDS(S, CC) do { \
    unsigned* b_ = lds + ((CC) & 1) * BUFW; \
    *(uint4*)(b_ + lwA) = S##x0; \
    *(uint4*)(b_ + lwB) = S##x1; \
    uint4 w0_, w1_; \
    WMUL(S##x0, S##f0, S##f1, w0_); \
    WMUL(S##x1, S##f0, S##f1, w1_); \
    *(uint4*)(b_ + TILE + lwA) = w0_; \
    *(uint4*)(b_ + TILE + lwB) = w1_; \
    *(uint4*)(b_ + 2 * TILE + lwA) = S##p0; \
    *(uint4*)(b_ + 2 * TILE + lwB) = S##p1; \
  } while (0)

  auto compute = [&](int cc) {
    const unsigned* bx = lds + (cc & 1) * BUFW;
#pragma unroll
    for (int ks = 0; ks < 4; ++ks) {
      const int col = (ks * 8 + hi * 4) ^ sw4;
      uint4 xr = *(const uint4*)(bx + axb + col);
      uint4 wr = *(const uint4*)(bx + TILE + axb + col);
      uint4 pr = *(const uint4*)(bx + 2 * TILE + pxb + col);
      v8s xf = frag8(xr), wf = frag8(wr), pf = frag8(pr);
      aD = __builtin_amdgcn_mfma_f32_32x32x16_bf16(xf, pf, aD, 0, 0, 0);
      aW = __builtin_amdgcn_mfma_f32_32x32x16_bf16(wf, pf, aW, 0, 0, 0);
    }
    if ((cc & 7) == 7) {
      // end of one t: sim = D/(xn*pn); s += exp(sim); n += exp(sim)*W.
      // |sim| <= 1 (cosine) -> exp bounded, no running max needed.
      const int t = tg * 4 + (cc >> 3);
      const float pnv = pn[(p0 + wn * 32 + fr) * 56 + t];
#pragma unroll
      for (int i = 0; i < 16; ++i) {
        const int drow = (i & 3) + 8 * (i >> 2) + 4 * hi;  // m74/m101 C/D map
        float xnv = xn[(b0 + wm * 32 + drow) * 56 + t];
        float den = fmaxf(xnv * pnv, 1e-8f);
        float sim = aD[i] * __builtin_amdgcn_rcpf(den);
        float e = __expf(sim);
        sac[i] += e;
        nac[i] = fmaf(e, aW[i], nac[i]);
        aD[i] = 0.f;
        aW[i] = 0.f;
      }
    }
  };

  // prologue
  LOAD_REGS(A, 0);
  STORE_LDS(A, 0);
  LOAD_REGS(B, 1);
  __syncthreads();

#pragma unroll 1
  for (int cc = 0; cc < 32; cc += 2) {
    if (cc + 1 < 32) STORE_LDS(B, cc + 1);
    if (cc + 2 < 32) LOAD_REGS(A, cc + 2);
    compute(cc);
    __syncthreads();
    if (cc + 2 < 32) STORE_LDS(A, cc + 2);
    if (cc + 3 < 32) LOAD_REGS(B, cc + 3);
    compute(cc + 1);
    __syncthreads();
  }

#undef LOAD_REGS
#undef WMUL
#undef STORE_LDS

  // write partials: part[(tg*2 + comp)*131072 + b*512 + p]
  float* psb = part + ((size_t)tg * 2 + 0) * 131072;
  float* pnb = part + ((size_t)tg * 2 + 1) * 131072;
#pragma unroll
  for (int i = 0; i < 16; ++i) {
    const int drow = (i & 3) + 8 * (i >> 2) + 4 * hi;
    const size_t o = (size_t)(b0 + wm * 32 + drow) * 512 + p0 + wn * 32 + fr;
    psb[o] = sac[i];
    pnb[o] = nac[i];
  }
}

// ===========================================================================
// MERGE: plain sums of the 14 t-group partials (no max needed), bias, relu.
// ===========================================================================
__global__ __launch_bounds__(256) void merge_kernel(
    const float* __restrict__ part, const float* __restrict__ fcb,
    float* __restrict__ out) {
  const int pair = blockIdx.x * 256 + threadIdx.x;
  float S = 0.f, N = 0.f;
#pragma unroll
  for (int k = 0; k < 14; ++k) {
    S += part[((size_t)k * 2 + 0) * 131072 + pair];
    N += part[((size_t)k * 2 + 1) * 131072 + pair];
  }
  float o = N * __builtin_amdgcn_rcpf(S) + fcb[0];
  out[pair] = fmaxf(o, 0.f);
}

// ===========================================================================
// FALLBACK (round-2 kernel, used only if ws_size is too small)
// ===========================================================================
__global__ __launch_bounds__(1024) void proto_mfma_kernel(
    const float* __restrict__ x, const float* __restrict__ proto,
    const float* __restrict__ fcw, const float* __restrict__ fcb,
    float* __restrict__ out) {
  __shared__ unsigned xs[56 * 289];
  __shared__ unsigned ps[56 * 145];
  __shared__ unsigned pws[56 * 145];

  const int tid = threadIdx.x;
  const int l = tid & 63;
  const int w = tid >> 6;
  const int bq = w & 1;
  const int tq = w >> 1;
  const int t0 = tq * 7;

  const int n = blockIdx.y * 32 + blockIdx.x;
  const int p0 = (n >> 3) * 16;
  const int b0 = (n & 7) * 32;

  const bool act = (l < 56);
  const int lt = l;

  const int xbase0 = ((b0 + 2 * w + 0) * kC) * kT + lt;
  const int xbase1 = ((b0 + 2 * w + 1) * kC) * kT + lt;
  const int pbase = ((p0 + w) * kC) * kT + lt;

  const int arow = l & 15;
  const int q2 = (l >> 4) << 1;
  const int xoff = (bq * 16 + arow) * 9 + q2;
  const int poff = arow * 9 + q2;

  v4f acc[7][2];
#pragma unroll
  for (int ti = 0; ti < 7; ++ti) {
    acc[ti][0] = v4f{0.f, 0.f, 0.f, 0.f};
    acc[ti][1] = v4f{0.f, 0.f, 0.f, 0.f};
  }
  float xn2a = 0.f, xn2b = 0.f, pn2 = 0.f;

#pragma unroll 1
  for (int st = 0; st < 32; ++st) {
    const int k0 = st * 16;
    if (act) {
#pragma unroll
      for (int r = 0; r < 16; ++r) {
        const int cw = r & 7;
        const int c = k0 + 2 * cw;
        const int ga = ((r >> 3) ? xbase1 : xbase0) + c * kT;
        float g0 = x[ga], g1 = x[ga + kT];
        if (r >> 3) xn2b = fmaf(g0, g0, fmaf(g1, g1, xn2b));
        else xn2a = fmaf(g0, g0, fmaf(g1, g1, xn2a));
        xs[lt * 289 + (2 * w + (r >> 3)) * 9 + cw] = pack_bf16(g0, g1);
      }
#pragma unroll
      for (int cw = 0; cw < 8; ++cw) {
        const int c = k0 + 2 * cw;
        const int ga = pbase + c * kT;
        float g0 = proto[ga], g1 = proto[ga + kT];
        pn2 = fmaf(g0, g0, fmaf(g1, g1, pn2));
        ps[lt * 145 + w * 9 + cw] = pack_bf16(g0, g1);
        float f0 = fcw[c], f1 = fcw[c + 1];
        pws[lt * 145 + w * 9 + cw] = pack_bf16(g0 * f0, g1 * f1);
      }
    }
    __syncthreads();
#pragma unroll
    for (int ti = 0; ti < 7; ++ti) {
      const int t = t0 + ti;
      unsigned xw0 = xs[t * 289 + xoff];
      unsigned xw1 = xs[t * 289 + xoff + 1];
      unsigned pw0 = ps[t * 145 + poff];
      unsigned pw1 = ps[t * 145 + poff + 1];
      unsigned ww0 = pws[t * 145 + poff];
      unsigned ww1 = pws[t * 145 + poff + 1];
      v4s af = frag2(xw0, xw1);
      v4s bf = frag2(pw0, pw1);
      v4s wf = frag2(ww0, ww1);
      acc[ti][0] = __builtin_amdgcn_mfma_f32_16x16x16bf16_1k(af, bf, acc[ti][0], 0, 0, 0);
      acc[ti][1] = __builtin_amdgcn_mfma_f32_16x16x16bf16_1k(af, wf, acc[ti][1], 0, 0, 0);
    }
    __syncthreads();
  }

  float* xnorm = (float*)ps;
  float* pnorm = xnorm + 32 * 56;
  if (act) {
    xnorm[(2 * w + 0) * 56 + lt] = xn2a;
    xnorm[(2 * w + 1) * 56 + lt] = xn2b;
    pnorm[w * 56 + lt] = pn2;
  }
  __syncthreads();

  float* fm = (float*)xs;
  float* fsum = fm + 4096;
  float* fnum = fsum + 4096;
  const int pc = arow;
  const int qq = l >> 4;
#pragma unroll
  for (int i = 0; i < 4; ++i) {
    const int bl = bq * 16 + 4 * qq + i;
    float m = -3.0e38f;
    float sims[7];
#pragma unroll
    for (int ti = 0; ti < 7; ++ti) {
      const int t = t0 + ti;
      float den = fmaxf(sqrtf(xnorm[bl * 56 + t]) * sqrtf(pnorm[pc * 56 + t]), 1e-8f);
      float s = acc[ti][0][i] / den;
      sims[ti] = s;
      m = fmaxf(m, s);
    }
    float se = 0.f, nu = 0.f;
#pragma unroll
    for (int ti = 0; ti < 7; ++ti) {
      float e = __expf(sims[ti] - m);
      se += e;
      nu = fmaf(e, acc[ti][1][i], nu);
    }
    const int pair = bl * 16 + pc;
    fm[tq * 512 + pair] = m;
    fsum[tq * 512 + pair] = se;
    fnum[tq * 512 + pair] = nu;
  }
  __syncthreads();

  if (tid < 512) {
    float M = -3.0e38f;
#pragma unroll
    for (int k = 0; k < 8; ++k) M = fmaxf(M, fm[k * 512 + tid]);
    float S = 0.f, N = 0.f;
#pragma unroll
    for (int k = 0; k < 8; ++k) {
      float sc = __expf(fm[k * 512 + tid] - M);
      S = fmaf(fsum[k * 512 + tid], sc, S);
      N = fmaf(fnum[k * 512 + tid], sc, N);
    }
    float o = N / S + fcb[0];
    out[(b0 + (tid >> 4)) * kP + p0 + (tid & 15)] = fmaxf(o, 0.f);
  }
}

// ===========================================================================
extern "C" void kernel_launch(void* const* d_in, const int* in_sizes, int n_in,
                              void* d_out, int out_size, void* d_ws, size_t ws_size,
                              hipStream_t stream) {
  const float* x = (const float*)d_in[0];
  const float* proto = (const float*)d_in[1];
  const float* fcw = (const float*)d_in[2];
  const float* fcb = (const float*)d_in[3];
  float* out = (float*)d_out;

  // ws layout (words): xt 3,670,016 | pt 7,340,032 | part 14*2*131072 =
  // 3,670,016 | xn 14,336 | pn 28,672  => 14,723,072 words = 58,892,288 B
  const size_t need = 58892288;
  if (ws_size >= need) {
    unsigned* xt = (unsigned*)d_ws;
    unsigned* ptb = xt + 3670016;
    float* partb = (float*)(xt + 11010048);
    float* xnb = (float*)(xt + 14680064);
    float* pnb = (float*)(xt + 14694400);

    hipLaunchKernelGGL(prep_kernel, dim3(kB + kP), dim3(512), 0, stream,
                       x, proto, xt, ptb, xnb, pnb);
    hipLaunchKernelGGL(proto_gemm_kernel, dim3(4, 8, 14), dim3(256), 0, stream,
                       xt, ptb, fcw, xnb, pnb, partb);
    hipLaunchKernelGGL(merge_kernel, dim3(512), dim3(256), 0, stream,
                       partb, fcb, out);
  } else {
    hipLaunchKernelGGL(proto_mfma_kernel, dim3(32, 8), dim3(1024), 0, stream,
                       x, proto, fcw, fcb, out);
  }
}